// Round 1
// baseline (20520.270 us; speedup 1.0000x reference)
//
#include <hip/hip_runtime.h>

#define HW    4096
#define DIMC  512
#define MEDC  1024
#define HRC   256
#define HSC   256
#define NBATCH 16

// ---------------- workspace layout (floats) ----------------
static const size_t XP_OFF    = 0;                         // 16*1024*4096 floats (xp; also r1 union)
static const size_t MEAN_OFF  = 67108864;                  // 4096
static const size_t AGG_OFF   = MEAN_OFF + 4096;           // 16*256*9
static const size_t TAP_OFF   = AGG_OFF + 36864;           // 16*256*9
static const size_t ROUTE_OFF = TAP_OFF + 36864;           // 16*4*1024
static const size_t SR_OFF    = ROUTE_OFF + 65536;         // 16*4*1024
static const size_t WS_END    = SR_OFF + 65536;

// ---------------- generic channel-major GEMM ----------------
// A: [B, K, 4096] channel-major; W: [Ntot, K]; C: [B, Ntot, 4096]
// EPI: 0 = none, 1 = bias+relu, 2 = StarReLU, 3 = bias+relu + column-mean atomic (no C write)
template<int EPI>
__global__ __launch_bounds__(256) void gemm_cm(
    const float* __restrict__ A, const float* __restrict__ W,
    const float* __restrict__ bias, float* __restrict__ C,
    float* __restrict__ meansum,
    const float* __restrict__ star_scale, const float* __restrict__ star_bias,
    int K, int Ntot)
{
  __shared__ __align__(16) float As[16][128];
  __shared__ __align__(16) float Bs[16][64];
  const int tid = threadIdx.x;
  const int hw0 = blockIdx.x * 128;
  const int n0g = blockIdx.y * 64;
  const int b   = blockIdx.z;
  const float* Ab = A + (size_t)b * K * HW + hw0;

  float acc[8][4];
#pragma unroll
  for (int i = 0; i < 8; i++)
#pragma unroll
    for (int j = 0; j < 4; j++) acc[i][j] = 0.f;

  const int m0 = (tid & 15) * 4;
  const int n0 = (tid >> 4) * 4;

  for (int k0 = 0; k0 < K; k0 += 16) {
#pragma unroll
    for (int i = 0; i < 8; i++) {
      int idx = i * 256 + tid;
      int kk = idx >> 7, mm = idx & 127;
      As[kk][mm] = Ab[(size_t)(k0 + kk) * HW + mm];
    }
#pragma unroll
    for (int i = 0; i < 4; i++) {
      int idx = i * 256 + tid;
      int kk = idx & 15, nn = idx >> 4;
      Bs[kk][nn] = W[(size_t)(n0g + nn) * K + k0 + kk];
    }
    __syncthreads();
#pragma unroll
    for (int kk = 0; kk < 16; kk++) {
      float4 a0 = *(const float4*)&As[kk][m0];
      float4 a1 = *(const float4*)&As[kk][m0 + 64];
      float4 bv = *(const float4*)&Bs[kk][n0];
      float av[8] = {a0.x, a0.y, a0.z, a0.w, a1.x, a1.y, a1.z, a1.w};
      float bw[4] = {bv.x, bv.y, bv.z, bv.w};
#pragma unroll
      for (int i = 0; i < 8; i++)
#pragma unroll
        for (int j = 0; j < 4; j++) acc[i][j] += av[i] * bw[j];
    }
    __syncthreads();
  }

  if (EPI == 3) {
#pragma unroll
    for (int j = 0; j < 4; j++) {
      float bia = bias[n0g + n0 + j];
      float cs = 0.f;
#pragma unroll
      for (int i = 0; i < 8; i++) {
        float v = acc[i][j] + bia;
        cs += (v > 0.f ? v : 0.f);
      }
      // reduce across the 16 consecutive lanes that share this n
      for (int off = 1; off < 16; off <<= 1) cs += __shfl_xor(cs, off);
      if ((tid & 15) == 0) atomicAdd(&meansum[b * Ntot + n0g + n0 + j], cs);
    }
    return;
  }

  float ss = 1.f, sb = 0.f;
  if (EPI == 2) { ss = star_scale[0]; sb = star_bias[0]; }
#pragma unroll
  for (int j = 0; j < 4; j++) {
    int n = n0g + n0 + j;
    float bia = (EPI == 1) ? bias[n] : 0.f;
    float* Cp = C + ((size_t)b * Ntot + n) * HW + hw0;
    float vv[8];
#pragma unroll
    for (int i = 0; i < 8; i++) {
      float v = acc[i][j];
      if (EPI == 1) { v += bia; v = v > 0.f ? v : 0.f; }
      if (EPI == 2) { v = v > 0.f ? v : 0.f; v = ss * v * v + sb; }
      vv[i] = v;
    }
    *(float4*)&Cp[m0]      = make_float4(vv[0], vv[1], vv[2], vv[3]);
    *(float4*)&Cp[m0 + 64] = make_float4(vv[4], vv[5], vv[6], vv[7]);
  }
}

// ---------------- sp_fc1 3x3 conv + relu + aggregate sums ----------------
// agg[b][o][9]: 0=T 1=R0 2=RH 3=C0 4=CW 5=s00 6=s0W 7=sH0 8=sHW
__global__ __launch_bounds__(256) void conv3_agg(
    const float* __restrict__ x, const float* __restrict__ w,
    const float* __restrict__ bias, float* __restrict__ agg)
{
  __shared__ float Asp[8][6][65];
  __shared__ float Wsp[64][8][9];
  const int tid = threadIdx.x;
  const int h0 = blockIdx.x * 4;
  const int o0 = blockIdx.y * 64;
  const int b  = blockIdx.z;
  const int og  = tid >> 5;        // 0..7  -> o block of 8
  const int mg  = tid & 31;
  const int h_l = mg >> 3;         // 0..3
  const int w0  = (mg & 7) * 8;    // 0..56

  float acc[8][8];
#pragma unroll
  for (int o = 0; o < 8; o++)
#pragma unroll
    for (int m = 0; m < 8; m++) acc[o][m] = 0.f;

  for (int c0 = 0; c0 < DIMC; c0 += 8) {
#pragma unroll
    for (int i = 0; i < 12; i++) {
      int idx = i * 256 + tid;
      int c = idx / 384; int rem = idx - c * 384;
      int r = rem >> 6;  int ww = rem & 63;
      int h = h0 + r - 1;
      float v = 0.f;
      if (h >= 0 && h < 64)
        v = x[((size_t)(b * DIMC + c0 + c)) * HW + h * 64 + ww];
      Asp[c][r][ww] = v;
    }
#pragma unroll
    for (int i = 0; i < 18; i++) {
      int idx = i * 256 + tid;
      int o = idx / 72; int rem = idx - o * 72;
      int c = rem / 9;  int t = rem - c * 9;
      Wsp[o][c][t] = w[((size_t)(o0 + o) * DIMC + c0 + c) * 9 + t];
    }
    __syncthreads();
#pragma unroll
    for (int c = 0; c < 8; c++) {
      float a[3][10];
#pragma unroll
      for (int rr = 0; rr < 3; rr++)
#pragma unroll
        for (int ww = 0; ww < 10; ww++) {
          int wc = w0 - 1 + ww;
          a[rr][ww] = (wc >= 0 && wc < 64) ? Asp[c][h_l + rr][wc] : 0.f;
        }
#pragma unroll
      for (int o = 0; o < 8; o++) {
#pragma unroll
        for (int t = 0; t < 9; t++) {
          float wv = Wsp[og * 8 + o][c][t];
          const int rr = t / 3, jj = t % 3;
#pragma unroll
          for (int m = 0; m < 8; m++) acc[o][m] += a[rr][m + jj] * wv;
        }
      }
    }
    __syncthreads();
  }

  const int h = h0 + h_l;
#pragma unroll
  for (int o = 0; o < 8; o++) {
    int oo = o0 + og * 8 + o;
    float bia = bias[oo];
    float v[8], T = 0.f;
#pragma unroll
    for (int m = 0; m < 8; m++) {
      float t = acc[o][m] + bia;
      v[m] = t > 0.f ? t : 0.f;
      T += v[m];
    }
    float* ag = &agg[((size_t)b * HSC + oo) * 9];
    atomicAdd(ag + 0, T);
    if (h == 0)  atomicAdd(ag + 1, T);
    if (h == 63) atomicAdd(ag + 2, T);
    if (w0 == 0)  atomicAdd(ag + 3, v[0]);
    if (w0 == 56) atomicAdd(ag + 4, v[7]);
    if (h == 0  && w0 == 0)  atomicAdd(ag + 5, v[0]);
    if (h == 0  && w0 == 56) atomicAdd(ag + 6, v[7]);
    if (h == 63 && w0 == 0)  atomicAdd(ag + 7, v[0]);
    if (h == 63 && w0 == 56) atomicAdd(ag + 8, v[7]);
  }
}

// ---------------- aggregates -> 9 tap sums (already /4096) ----------------
__global__ void tap_compute(const float* __restrict__ agg, float* __restrict__ tap)
{
  int b = blockIdx.x; int c = threadIdx.x;
  const float* a = &agg[((size_t)b * HSC + c) * 9];
  float T = a[0], R0 = a[1], RH = a[2], C0 = a[3], CW = a[4];
  float s00 = a[5], s0W = a[6], sH0 = a[7], sHW = a[8];
  float* tp = &tap[((size_t)b * HSC + c) * 9];
#pragma unroll
  for (int i = 0; i < 3; i++)
#pragma unroll
    for (int j = 0; j < 3; j++) {
      int di = i - 1, dj = j - 1;
      float v = T;
      if (di == -1) v -= RH; else if (di == 1) v -= R0;
      if (dj == -1) v -= CW; else if (dj == 1) v -= C0;
      if (di == -1 && dj == -1) v += sHW;
      if (di == -1 && dj ==  1) v += sH0;
      if (di ==  1 && dj == -1) v += s0W;
      if (di ==  1 && dj ==  1) v += s00;
      tp[i * 3 + j] = v * (1.f / 4096.f);
    }
}

// ---------------- routing fc2 + softmax over NF ----------------
__global__ __launch_bounds__(256) void route_softmax(
    const float* __restrict__ meansum, const float* __restrict__ W,
    const float* __restrict__ bias, float* __restrict__ route)
{
  __shared__ float mv[HRC];
  int b = blockIdx.y;
  int m = blockIdx.x * 256 + threadIdx.x;
  mv[threadIdx.x] = meansum[b * HRC + threadIdx.x] * (1.f / 4096.f);
  __syncthreads();
  float l[4];
#pragma unroll
  for (int f = 0; f < 4; f++) {
    int o = f * MEDC + m;
    float accv = bias[o];
    const float* wr = &W[(size_t)o * HRC];
    for (int c = 0; c < HRC; c++) accv += wr[c] * mv[c];
    l[f] = accv;
  }
  float mx = fmaxf(fmaxf(l[0], l[1]), fmaxf(l[2], l[3]));
  float e[4], s = 0.f;
#pragma unroll
  for (int f = 0; f < 4; f++) { e[f] = expf(l[f] - mx); s += e[f]; }
  float inv = 1.f / s;
#pragma unroll
  for (int f = 0; f < 4; f++) route[((size_t)b * 4 + f) * MEDC + m] = e[f] * inv;
}

// ---------------- spatial routing fc2 (9-tap) + softmax ----------------
__global__ __launch_bounds__(256) void sproute_softmax(
    const float* __restrict__ tap, const float* __restrict__ W,
    const float* __restrict__ bias, float* __restrict__ sroute)
{
  __shared__ float tv[HSC * 9];
  int b = blockIdx.y;
  int m = blockIdx.x * 256 + threadIdx.x;
#pragma unroll
  for (int i = 0; i < 9; i++) {
    int idx = i * 256 + threadIdx.x;
    tv[idx] = tap[(size_t)b * HSC * 9 + idx];
  }
  __syncthreads();
  float l[4];
#pragma unroll
  for (int f = 0; f < 4; f++) {
    int o = f * MEDC + m;
    float accv = bias[o];
    const float* wr = &W[(size_t)o * HSC * 9];
    for (int ct = 0; ct < HSC * 9; ct++) accv += wr[ct] * tv[ct];
    l[f] = accv;
  }
  float mx = fmaxf(fmaxf(l[0], l[1]), fmaxf(l[2], l[3]));
  float e[4], s = 0.f;
#pragma unroll
  for (int f = 0; f < 4; f++) { e[f] = expf(l[f] - mx); s += e[f]; }
  float inv = 1.f / s;
#pragma unroll
  for (int f = 0; f < 4; f++) sroute[((size_t)b * 4 + f) * MEDC + m] = e[f] * inv;
}

// ---------------- 2D DFT filter + spatial gating, in-place on xp ----------------
__global__ __launch_bounds__(256) void fft_filter(
    float* __restrict__ xp, const float* __restrict__ route,
    const float* __restrict__ sroute, const float* __restrict__ cw,
    const float* __restrict__ spw)
{
  __shared__ float X[64][65];
  __shared__ float Fre[64][34], Fim[64][34];
  __shared__ float Gre[64][34], Gim[64][34];
  __shared__ float twc[64], tws[64];
  const int tid = threadIdx.x;
  const int blk = blockIdx.x;
  const int b = blk >> 10;
  const int m = blk & 1023;
  float* img = xp + (size_t)blk * HW;

  if (tid < 64) {
    float ang = (2.f * 3.14159265358979323846f / 64.f) * (float)tid;
    twc[tid] = cosf(ang); tws[tid] = sinf(ang);
  }
  float r[4], s4[4];
#pragma unroll
  for (int f = 0; f < 4; f++) {
    r[f]  = route[((size_t)b * 4 + f) * MEDC + m];
    s4[f] = sroute[((size_t)b * 4 + f) * MEDC + m];
  }
#pragma unroll
  for (int i = 0; i < 16; i++) {
    int idx = i * 256 + tid;
    X[idx >> 6][idx & 63] = img[idx];
  }
  __syncthreads();

  // forward rfft along w:  F[h][k] = sum_w X[h][w] e^{-2pi i wk/64}
  for (int idx = tid; idx < 64 * 33; idx += 256) {
    int h = idx / 33; int k = idx - h * 33;
    float re = 0.f, im = 0.f;
    for (int w = 0; w < 64; w++) {
      float xv = X[h][w];
      int ai = (w * k) & 63;
      re += xv * twc[ai];
      im -= xv * tws[ai];
    }
    Fre[h][k] = re; Fim[h][k] = im;
  }
  __syncthreads();

  // forward full fft along h + weight multiply (+ ortho 1/4096)
  for (int idx = tid; idx < 64 * 33; idx += 256) {
    int kh = idx / 33; int k = idx - kh * 33;
    float re = 0.f, im = 0.f;
    for (int h = 0; h < 64; h++) {
      int ai = (h * kh) & 63;
      float c = twc[ai], s = tws[ai];
      float fr = Fre[h][k], fi = Fim[h][k];
      re += fr * c + fi * s;
      im += fi * c - fr * s;
    }
    const float* cwp = &cw[(size_t)(kh * 33 + k) * 8];
    float wre = 0.f, wim = 0.f;
#pragma unroll
    for (int f = 0; f < 4; f++) { wre += r[f] * cwp[2 * f]; wim += r[f] * cwp[2 * f + 1]; }
    Gre[kh][k] = (re * wre - im * wim) * (1.f / 4096.f);
    Gim[kh][k] = (re * wim + im * wre) * (1.f / 4096.f);
  }
  __syncthreads();

  // inverse fft along h
  for (int idx = tid; idx < 64 * 33; idx += 256) {
    int h = idx / 33; int k = idx - h * 33;
    float re = 0.f, im = 0.f;
    for (int kh = 0; kh < 64; kh++) {
      int ai = (h * kh) & 63;
      float c = twc[ai], s = tws[ai];
      float gr = Gre[kh][k], gi = Gim[kh][k];
      re += gr * c - gi * s;
      im += gi * c + gr * s;
    }
    Fre[h][k] = re; Fim[h][k] = im;
  }
  __syncthreads();

  // inverse rfft along w (imag of bins 0,32 dropped) + gating epilogue
#pragma unroll
  for (int i = 0; i < 16; i++) {
    int idx = i * 256 + tid;
    int h = idx >> 6, w = idx & 63;
    float xs = 0.f;
    for (int k = 0; k <= 32; k++) {
      int ai = (k * w) & 63;
      float v = Fre[h][k] * twc[ai] - Fim[h][k] * tws[ai];
      xs += (k == 0 || k == 32) ? v : 2.f * v;
    }
    const float* sp = &spw[(size_t)idx * 4];
    float sw = s4[0] * sp[0] + s4[1] * sp[1] + s4[2] * sp[2] + s4[3] * sp[3];
    img[idx] = X[h][w] * sw + xs;
  }
}

extern "C" void kernel_launch(void* const* d_in, const int* in_sizes, int n_in,
                              void* d_out, int out_size, void* d_ws, size_t ws_size,
                              hipStream_t stream) {
  const float* x          = (const float*)d_in[0];
  const float* w_pw1      = (const float*)d_in[1];
  const float* w_pw2      = (const float*)d_in[2];
  const float* star_scale = (const float*)d_in[3];
  const float* star_bias  = (const float*)d_in[4];
  const float* rw1w = (const float*)d_in[5];
  const float* rw1b = (const float*)d_in[6];
  const float* rwcw = (const float*)d_in[7];
  const float* rwcb = (const float*)d_in[8];
  const float* rw2w = (const float*)d_in[9];
  const float* rw2b = (const float*)d_in[10];
  const float* sp1w = (const float*)d_in[11];
  const float* sp1b = (const float*)d_in[12];
  const float* sp2w = (const float*)d_in[13];
  const float* sp2b = (const float*)d_in[14];
  const float* cw   = (const float*)d_in[15];
  const float* spw  = (const float*)d_in[16];

  if (ws_size < WS_END * sizeof(float)) return;  // insufficient scratch

  float* ws = (float*)d_ws;
  float* xp      = ws + XP_OFF;
  float* r1      = ws + XP_OFF;      // union: dead before xp is written
  float* meansum = ws + MEAN_OFF;
  float* agg     = ws + AGG_OFF;
  float* tap     = ws + TAP_OFF;
  float* route   = ws + ROUTE_OFF;
  float* sr      = ws + SR_OFF;
  float* out = (float*)d_out;

  hipMemsetAsync(meansum, 0, (4096 + 36864) * sizeof(float), stream);

  // routing branch
  gemm_cm<1><<<dim3(32, 4, 16), 256, 0, stream>>>(x, rw1w, rw1b, r1, nullptr, nullptr, nullptr, DIMC, HRC);
  gemm_cm<3><<<dim3(32, 4, 16), 256, 0, stream>>>(r1, rwcw, rwcb, nullptr, meansum, nullptr, nullptr, HRC, HRC);
  route_softmax<<<dim3(4, 16), 256, 0, stream>>>(meansum, rw2w, rw2b, route);

  // spatial routing branch
  conv3_agg<<<dim3(16, 4, 16), 256, 0, stream>>>(x, sp1w, sp1b, agg);
  tap_compute<<<16, 256, 0, stream>>>(agg, tap);
  sproute_softmax<<<dim3(4, 16), 256, 0, stream>>>(tap, sp2w, sp2b, sr);

  // main path
  gemm_cm<2><<<dim3(32, 16, 16), 256, 0, stream>>>(x, w_pw1, nullptr, xp, nullptr, star_scale, star_bias, DIMC, MEDC);
  fft_filter<<<16384, 256, 0, stream>>>(xp, route, sr, cw, spw);
  gemm_cm<0><<<dim3(32, 8, 16), 256, 0, stream>>>(xp, w_pw2, nullptr, out, nullptr, nullptr, nullptr, MEDC, DIMC);
}

// Round 2
// 7442.578 us; speedup vs baseline: 2.7571x; 2.7571x over previous
//
#include <hip/hip_runtime.h>

#define HW    4096
#define DIMC  512
#define MEDC  1024
#define HRC   256
#define HSC   256
#define NBATCH 16

// ---------------- workspace layout (floats) ----------------
static const size_t XP_OFF    = 0;                         // 16*1024*4096 floats (xp; also r1 union)
static const size_t MEAN_OFF  = 67108864;                  // 4096
static const size_t AGG_OFF   = MEAN_OFF + 4096;           // 16*256*9
static const size_t TAP_OFF   = AGG_OFF + 36864;           // 16*256*9
static const size_t ROUTE_OFF = TAP_OFF + 36864;           // 16*4*1024
static const size_t SR_OFF    = ROUTE_OFF + 65536;         // 16*4*1024
static const size_t WS_END    = SR_OFF + 65536;

// ---------------- generic channel-major GEMM ----------------
// A: [B, K, 4096] channel-major; W: [Ntot, K]; C: [B, Ntot, 4096]
// EPI: 0 = none, 1 = bias+relu, 2 = StarReLU, 3 = bias+relu + column-mean atomic (no C write)
template<int EPI>
__global__ __launch_bounds__(256) void gemm_cm(
    const float* __restrict__ A, const float* __restrict__ W,
    const float* __restrict__ bias, float* __restrict__ C,
    float* __restrict__ meansum,
    const float* __restrict__ star_scale, const float* __restrict__ star_bias,
    int K, int Ntot)
{
  __shared__ __align__(16) float As[16][128];
  __shared__ __align__(16) float Bs[16][64];
  const int tid = threadIdx.x;
  const int hw0 = blockIdx.x * 128;
  const int n0g = blockIdx.y * 64;
  const int b   = blockIdx.z;
  const float* Ab = A + (size_t)b * K * HW + hw0;

  float acc[8][4];
#pragma unroll
  for (int i = 0; i < 8; i++)
#pragma unroll
    for (int j = 0; j < 4; j++) acc[i][j] = 0.f;

  const int m0 = (tid & 15) * 4;
  const int n0 = (tid >> 4) * 4;

  for (int k0 = 0; k0 < K; k0 += 16) {
#pragma unroll
    for (int i = 0; i < 8; i++) {
      int idx = i * 256 + tid;
      int kk = idx >> 7, mm = idx & 127;
      As[kk][mm] = Ab[(size_t)(k0 + kk) * HW + mm];
    }
#pragma unroll
    for (int i = 0; i < 4; i++) {
      int idx = i * 256 + tid;
      int kk = idx & 15, nn = idx >> 4;
      Bs[kk][nn] = W[(size_t)(n0g + nn) * K + k0 + kk];
    }
    __syncthreads();
#pragma unroll
    for (int kk = 0; kk < 16; kk++) {
      float4 a0 = *(const float4*)&As[kk][m0];
      float4 a1 = *(const float4*)&As[kk][m0 + 64];
      float4 bv = *(const float4*)&Bs[kk][n0];
      float av[8] = {a0.x, a0.y, a0.z, a0.w, a1.x, a1.y, a1.z, a1.w};
      float bw[4] = {bv.x, bv.y, bv.z, bv.w};
#pragma unroll
      for (int i = 0; i < 8; i++)
#pragma unroll
        for (int j = 0; j < 4; j++) acc[i][j] += av[i] * bw[j];
    }
    __syncthreads();
  }

  if (EPI == 3) {
#pragma unroll
    for (int j = 0; j < 4; j++) {
      float bia = bias[n0g + n0 + j];
      float cs = 0.f;
#pragma unroll
      for (int i = 0; i < 8; i++) {
        float v = acc[i][j] + bia;
        cs += (v > 0.f ? v : 0.f);
      }
      for (int off = 1; off < 16; off <<= 1) cs += __shfl_xor(cs, off);
      if ((tid & 15) == 0) atomicAdd(&meansum[b * Ntot + n0g + n0 + j], cs);
    }
    return;
  }

  float ss = 1.f, sb = 0.f;
  if (EPI == 2) { ss = star_scale[0]; sb = star_bias[0]; }
#pragma unroll
  for (int j = 0; j < 4; j++) {
    int n = n0g + n0 + j;
    float bia = (EPI == 1) ? bias[n] : 0.f;
    float* Cp = C + ((size_t)b * Ntot + n) * HW + hw0;
    float vv[8];
#pragma unroll
    for (int i = 0; i < 8; i++) {
      float v = acc[i][j];
      if (EPI == 1) { v += bia; v = v > 0.f ? v : 0.f; }
      if (EPI == 2) { v = v > 0.f ? v : 0.f; v = ss * v * v + sb; }
      vv[i] = v;
    }
    *(float4*)&Cp[m0]      = make_float4(vv[0], vv[1], vv[2], vv[3]);
    *(float4*)&Cp[m0 + 64] = make_float4(vv[4], vv[5], vv[6], vv[7]);
  }
}

// ---------------- sp_fc1 3x3 conv + relu + aggregate sums (lean implicit GEMM) ----------------
// agg[b][o][9]: 0=T 1=R0 2=RH 3=C0 4=CW 5=s00 6=s0W 7=sH0 8=sHW
// Block: 2 pixel rows (128 px) x 64 out channels, one batch. 256 thr = 8 o-groups x 32 m-lanes.
// Each thread: 2x2 pixels x 8 o -> acc[8][4] = 32 regs; window 16 regs; no spill.
__global__ __launch_bounds__(256, 3) void conv3_gemm(
    const float* __restrict__ x, const float* __restrict__ w,
    const float* __restrict__ bias, float* __restrict__ agg)
{
  __shared__ float Xs[8][4][66];     // 8 ch, rows h0-1..h0+2, cols -1..64
  __shared__ __align__(16) float Ws2[8][64][12];  // [c][o][tap 0..8, pad 12]
  const int tid = threadIdx.x;
  const int bx = blockIdx.x;         // 0..31 -> rows 2bx, 2bx+1
  const int o0 = blockIdx.y * 64;
  const int b  = blockIdx.z;
  const int ot = tid >> 5;           // 0..7
  const int mt = tid & 31;           // 0..31 -> cols 2mt, 2mt+1
  const int h0 = bx * 2;

  float acc[8][4];
#pragma unroll
  for (int o = 0; o < 8; o++)
#pragma unroll
    for (int p = 0; p < 4; p++) acc[o][p] = 0.f;

  for (int c0 = 0; c0 < DIMC; c0 += 8) {
    // stage x slab: 8 ch x 4 rows x 66 cols (zero-padded halo)
#pragma unroll
    for (int i = 0; i < 9; i++) {
      int idx = i * 256 + tid;
      if (idx < 2112) {
        int c = idx / 264; int rem = idx - c * 264;
        int r = rem / 66;  int cc = rem - r * 66;
        int h = h0 + r - 1;
        int col = cc - 1;
        float v = 0.f;
        if (h >= 0 && h < 64 && col >= 0 && col < 64)
          v = x[((size_t)(b * DIMC + c0 + c)) * HW + h * 64 + col];
        Xs[c][r][cc] = v;
      }
    }
    // stage weights: [c][o][t], 12-padded for float4 reads
#pragma unroll
    for (int i = 0; i < 18; i++) {
      int idx = i * 256 + tid;         // 4608 total
      int o = idx / 72; int k = idx - o * 72;
      int c = k / 9;    int t = k - c * 9;
      Ws2[c][o][t] = w[((size_t)(o0 + o) * DIMC + c0 + c) * 9 + t];
    }
    __syncthreads();

#pragma unroll
    for (int c = 0; c < 8; c++) {
      float win[4][4];
#pragma unroll
      for (int r = 0; r < 4; r++) {
        float2 a0 = *(const float2*)&Xs[c][r][2 * mt];
        float2 a1 = *(const float2*)&Xs[c][r][2 * mt + 2];
        win[r][0] = a0.x; win[r][1] = a0.y; win[r][2] = a1.x; win[r][3] = a1.y;
      }
#pragma unroll
      for (int o = 0; o < 8; o++) {
        float4 wv0 = *(const float4*)&Ws2[c][ot * 8 + o][0];
        float4 wv1 = *(const float4*)&Ws2[c][ot * 8 + o][4];
        float wv8  = Ws2[c][ot * 8 + o][8];
        float wv[9] = {wv0.x, wv0.y, wv0.z, wv0.w, wv1.x, wv1.y, wv1.z, wv1.w, wv8};
#pragma unroll
        for (int t = 0; t < 9; t++) {
          const int di = t / 3, dj = t % 3;
          acc[o][0] += win[0 + di][0 + dj] * wv[t];
          acc[o][1] += win[0 + di][1 + dj] * wv[t];
          acc[o][2] += win[1 + di][0 + dj] * wv[t];
          acc[o][3] += win[1 + di][1 + dj] * wv[t];
        }
      }
    }
    __syncthreads();
  }

  // epilogue: relu + aggregate sums
#pragma unroll
  for (int o = 0; o < 8; o++) {
    int oo = o0 + ot * 8 + o;
    float bia = bias[oo];
    float v00 = fmaxf(acc[o][0] + bia, 0.f);
    float v01 = fmaxf(acc[o][1] + bia, 0.f);
    float v10 = fmaxf(acc[o][2] + bia, 0.f);
    float v11 = fmaxf(acc[o][3] + bia, 0.f);
    float* ag = &agg[((size_t)b * HSC + oo) * 9];

    float T = v00 + v01 + v10 + v11;
#pragma unroll
    for (int off = 16; off > 0; off >>= 1) T += __shfl_xor(T, off);
    if (mt == 0) atomicAdd(ag + 0, T);

    if (bx == 0) {
      float rs = v00 + v01;
#pragma unroll
      for (int off = 16; off > 0; off >>= 1) rs += __shfl_xor(rs, off);
      if (mt == 0) { atomicAdd(ag + 1, rs); atomicAdd(ag + 5, v00); }
      if (mt == 31) atomicAdd(ag + 6, v01);
    }
    if (bx == 31) {
      float rs = v10 + v11;
#pragma unroll
      for (int off = 16; off > 0; off >>= 1) rs += __shfl_xor(rs, off);
      if (mt == 0) { atomicAdd(ag + 2, rs); atomicAdd(ag + 7, v10); }
      if (mt == 31) atomicAdd(ag + 8, v11);
    }
    if (mt == 0)  atomicAdd(ag + 3, v00 + v10);
    if (mt == 31) atomicAdd(ag + 4, v01 + v11);
  }
}

// ---------------- aggregates -> 9 tap sums (already /4096) ----------------
__global__ void tap_compute(const float* __restrict__ agg, float* __restrict__ tap)
{
  int b = blockIdx.x; int c = threadIdx.x;
  const float* a = &agg[((size_t)b * HSC + c) * 9];
  float T = a[0], R0 = a[1], RH = a[2], C0 = a[3], CW = a[4];
  float s00 = a[5], s0W = a[6], sH0 = a[7], sHW = a[8];
  float* tp = &tap[((size_t)b * HSC + c) * 9];
#pragma unroll
  for (int i = 0; i < 3; i++)
#pragma unroll
    for (int j = 0; j < 3; j++) {
      int di = i - 1, dj = j - 1;
      float v = T;
      if (di == -1) v -= RH; else if (di == 1) v -= R0;
      if (dj == -1) v -= CW; else if (dj == 1) v -= C0;
      if (di == -1 && dj == -1) v += sHW;
      if (di == -1 && dj ==  1) v += sH0;
      if (di ==  1 && dj == -1) v += s0W;
      if (di ==  1 && dj ==  1) v += s00;
      tp[i * 3 + j] = v * (1.f / 4096.f);
    }
}

// ---------------- routing fc2 + softmax over NF ----------------
__global__ __launch_bounds__(256) void route_softmax(
    const float* __restrict__ meansum, const float* __restrict__ W,
    const float* __restrict__ bias, float* __restrict__ route)
{
  __shared__ float mv[HRC];
  int b = blockIdx.y;
  int m = blockIdx.x * 256 + threadIdx.x;
  mv[threadIdx.x] = meansum[b * HRC + threadIdx.x] * (1.f / 4096.f);
  __syncthreads();
  float l[4];
#pragma unroll
  for (int f = 0; f < 4; f++) {
    int o = f * MEDC + m;
    float accv = bias[o];
    const float* wr = &W[(size_t)o * HRC];
    for (int c = 0; c < HRC; c++) accv += wr[c] * mv[c];
    l[f] = accv;
  }
  float mx = fmaxf(fmaxf(l[0], l[1]), fmaxf(l[2], l[3]));
  float e[4], s = 0.f;
#pragma unroll
  for (int f = 0; f < 4; f++) { e[f] = expf(l[f] - mx); s += e[f]; }
  float inv = 1.f / s;
#pragma unroll
  for (int f = 0; f < 4; f++) route[((size_t)b * 4 + f) * MEDC + m] = e[f] * inv;
}

// ---------------- spatial routing fc2 (9-tap) + softmax ----------------
__global__ __launch_bounds__(256) void sproute_softmax(
    const float* __restrict__ tap, const float* __restrict__ W,
    const float* __restrict__ bias, float* __restrict__ sroute)
{
  __shared__ float tv[HSC * 9];
  int b = blockIdx.y;
  int m = blockIdx.x * 256 + threadIdx.x;
#pragma unroll
  for (int i = 0; i < 9; i++) {
    int idx = i * 256 + threadIdx.x;
    tv[idx] = tap[(size_t)b * HSC * 9 + idx];
  }
  __syncthreads();
  float l[4];
#pragma unroll
  for (int f = 0; f < 4; f++) {
    int o = f * MEDC + m;
    float accv = bias[o];
    const float* wr = &W[(size_t)o * HSC * 9];
    for (int ct = 0; ct < HSC * 9; ct++) accv += wr[ct] * tv[ct];
    l[f] = accv;
  }
  float mx = fmaxf(fmaxf(l[0], l[1]), fmaxf(l[2], l[3]));
  float e[4], s = 0.f;
#pragma unroll
  for (int f = 0; f < 4; f++) { e[f] = expf(l[f] - mx); s += e[f]; }
  float inv = 1.f / s;
#pragma unroll
  for (int f = 0; f < 4; f++) sroute[((size_t)b * 4 + f) * MEDC + m] = e[f] * inv;
}

// ---------------- 2D DFT filter + spatial gating, in-place on xp ----------------
__global__ __launch_bounds__(256) void fft_filter(
    float* __restrict__ xp, const float* __restrict__ route,
    const float* __restrict__ sroute, const float* __restrict__ cw,
    const float* __restrict__ spw)
{
  __shared__ float X[64][65];
  __shared__ float Fre[64][34], Fim[64][34];
  __shared__ float Gre[64][34], Gim[64][34];
  __shared__ float twc[64], tws[64];
  const int tid = threadIdx.x;
  const int blk = blockIdx.x;
  const int b = blk >> 10;
  const int m = blk & 1023;
  float* img = xp + (size_t)blk * HW;

  if (tid < 64) {
    float ang = (2.f * 3.14159265358979323846f / 64.f) * (float)tid;
    twc[tid] = cosf(ang); tws[tid] = sinf(ang);
  }
  float r[4], s4[4];
#pragma unroll
  for (int f = 0; f < 4; f++) {
    r[f]  = route[((size_t)b * 4 + f) * MEDC + m];
    s4[f] = sroute[((size_t)b * 4 + f) * MEDC + m];
  }
#pragma unroll
  for (int i = 0; i < 16; i++) {
    int idx = i * 256 + tid;
    X[idx >> 6][idx & 63] = img[idx];
  }
  __syncthreads();

  for (int idx = tid; idx < 64 * 33; idx += 256) {
    int h = idx / 33; int k = idx - h * 33;
    float re = 0.f, im = 0.f;
    for (int w = 0; w < 64; w++) {
      float xv = X[h][w];
      int ai = (w * k) & 63;
      re += xv * twc[ai];
      im -= xv * tws[ai];
    }
    Fre[h][k] = re; Fim[h][k] = im;
  }
  __syncthreads();

  for (int idx = tid; idx < 64 * 33; idx += 256) {
    int kh = idx / 33; int k = idx - kh * 33;
    float re = 0.f, im = 0.f;
    for (int h = 0; h < 64; h++) {
      int ai = (h * kh) & 63;
      float c = twc[ai], s = tws[ai];
      float fr = Fre[h][k], fi = Fim[h][k];
      re += fr * c + fi * s;
      im += fi * c - fr * s;
    }
    const float* cwp = &cw[(size_t)(kh * 33 + k) * 8];
    float wre = 0.f, wim = 0.f;
#pragma unroll
    for (int f = 0; f < 4; f++) { wre += r[f] * cwp[2 * f]; wim += r[f] * cwp[2 * f + 1]; }
    Gre[kh][k] = (re * wre - im * wim) * (1.f / 4096.f);
    Gim[kh][k] = (re * wim + im * wre) * (1.f / 4096.f);
  }
  __syncthreads();

  for (int idx = tid; idx < 64 * 33; idx += 256) {
    int h = idx / 33; int k = idx - h * 33;
    float re = 0.f, im = 0.f;
    for (int kh = 0; kh < 64; kh++) {
      int ai = (h * kh) & 63;
      float c = twc[ai], s = tws[ai];
      float gr = Gre[kh][k], gi = Gim[kh][k];
      re += gr * c - gi * s;
      im += gi * c + gr * s;
    }
    Fre[h][k] = re; Fim[h][k] = im;
  }
  __syncthreads();

#pragma unroll
  for (int i = 0; i < 16; i++) {
    int idx = i * 256 + tid;
    int h = idx >> 6, w = idx & 63;
    float xs = 0.f;
    for (int k = 0; k <= 32; k++) {
      int ai = (k * w) & 63;
      float v = Fre[h][k] * twc[ai] - Fim[h][k] * tws[ai];
      xs += (k == 0 || k == 32) ? v : 2.f * v;
    }
    const float* sp = &spw[(size_t)idx * 4];
    float sw = s4[0] * sp[0] + s4[1] * sp[1] + s4[2] * sp[2] + s4[3] * sp[3];
    img[idx] = X[h][w] * sw + xs;
  }
}

extern "C" void kernel_launch(void* const* d_in, const int* in_sizes, int n_in,
                              void* d_out, int out_size, void* d_ws, size_t ws_size,
                              hipStream_t stream) {
  const float* x          = (const float*)d_in[0];
  const float* w_pw1      = (const float*)d_in[1];
  const float* w_pw2      = (const float*)d_in[2];
  const float* star_scale = (const float*)d_in[3];
  const float* star_bias  = (const float*)d_in[4];
  const float* rw1w = (const float*)d_in[5];
  const float* rw1b = (const float*)d_in[6];
  const float* rwcw = (const float*)d_in[7];
  const float* rwcb = (const float*)d_in[8];
  const float* rw2w = (const float*)d_in[9];
  const float* rw2b = (const float*)d_in[10];
  const float* sp1w = (const float*)d_in[11];
  const float* sp1b = (const float*)d_in[12];
  const float* sp2w = (const float*)d_in[13];
  const float* sp2b = (const float*)d_in[14];
  const float* cw   = (const float*)d_in[15];
  const float* spw  = (const float*)d_in[16];

  if (ws_size < WS_END * sizeof(float)) return;

  float* ws = (float*)d_ws;
  float* xp      = ws + XP_OFF;
  float* r1      = ws + XP_OFF;
  float* meansum = ws + MEAN_OFF;
  float* agg     = ws + AGG_OFF;
  float* tap     = ws + TAP_OFF;
  float* route   = ws + ROUTE_OFF;
  float* sr      = ws + SR_OFF;
  float* out = (float*)d_out;

  hipMemsetAsync(meansum, 0, (4096 + 36864) * sizeof(float), stream);

  // routing branch
  gemm_cm<1><<<dim3(32, 4, 16), 256, 0, stream>>>(x, rw1w, rw1b, r1, nullptr, nullptr, nullptr, DIMC, HRC);
  gemm_cm<3><<<dim3(32, 4, 16), 256, 0, stream>>>(r1, rwcw, rwcb, nullptr, meansum, nullptr, nullptr, HRC, HRC);
  route_softmax<<<dim3(4, 16), 256, 0, stream>>>(meansum, rw2w, rw2b, route);

  // spatial routing branch
  conv3_gemm<<<dim3(32, 4, 16), 256, 0, stream>>>(x, sp1w, sp1b, agg);
  tap_compute<<<16, 256, 0, stream>>>(agg, tap);
  sproute_softmax<<<dim3(4, 16), 256, 0, stream>>>(tap, sp2w, sp2b, sr);

  // main path
  gemm_cm<2><<<dim3(32, 16, 16), 256, 0, stream>>>(x, w_pw1, nullptr, xp, nullptr, star_scale, star_bias, DIMC, MEDC);
  fft_filter<<<16384, 256, 0, stream>>>(xp, route, sr, cw, spw);
  gemm_cm<0><<<dim3(32, 8, 16), 256, 0, stream>>>(xp, w_pw2, nullptr, out, nullptr, nullptr, nullptr, MEDC, DIMC);
}

// Round 4
// 5305.729 us; speedup vs baseline: 3.8676x; 1.4027x over previous
//
#include <hip/hip_runtime.h>

#define HW    4096
#define DIMC  512
#define MEDC  1024
#define HRC   256
#define HSC   256
#define NBATCH 16

// ---------------- workspace layout (floats) ----------------
static const size_t XP_OFF    = 0;                         // 16*1024*4096 floats (xp; also r1 union)
static const size_t MEAN_OFF  = 67108864;                  // 4096
static const size_t AGG_OFF   = MEAN_OFF + 4096;           // 16*256*9
static const size_t TAP_OFF   = AGG_OFF + 36864;           // 16*256*9
static const size_t ROUTE_OFF = TAP_OFF + 36864;           // 16*4*1024
static const size_t SR_OFF    = ROUTE_OFF + 65536;         // 16*4*1024
static const size_t WS_END    = SR_OFF + 65536;

// ---------------- generic channel-major GEMM ----------------
template<int EPI>
__global__ __launch_bounds__(256) void gemm_cm(
    const float* __restrict__ A, const float* __restrict__ W,
    const float* __restrict__ bias, float* __restrict__ C,
    float* __restrict__ meansum,
    const float* __restrict__ star_scale, const float* __restrict__ star_bias,
    int K, int Ntot)
{
  __shared__ __align__(16) float As[16][128];
  __shared__ __align__(16) float Bs[16][64];
  const int tid = threadIdx.x;
  const int hw0 = blockIdx.x * 128;
  const int n0g = blockIdx.y * 64;
  const int b   = blockIdx.z;
  const float* Ab = A + (size_t)b * K * HW + hw0;

  float acc[8][4];
#pragma unroll
  for (int i = 0; i < 8; i++)
#pragma unroll
    for (int j = 0; j < 4; j++) acc[i][j] = 0.f;

  const int m0 = (tid & 15) * 4;
  const int n0 = (tid >> 4) * 4;

  for (int k0 = 0; k0 < K; k0 += 16) {
#pragma unroll
    for (int i = 0; i < 8; i++) {
      int idx = i * 256 + tid;
      int kk = idx >> 7, mm = idx & 127;
      As[kk][mm] = Ab[(size_t)(k0 + kk) * HW + mm];
    }
#pragma unroll
    for (int i = 0; i < 4; i++) {
      int idx = i * 256 + tid;
      int kk = idx & 15, nn = idx >> 4;
      Bs[kk][nn] = W[(size_t)(n0g + nn) * K + k0 + kk];
    }
    __syncthreads();
#pragma unroll
    for (int kk = 0; kk < 16; kk++) {
      float4 a0 = *(const float4*)&As[kk][m0];
      float4 a1 = *(const float4*)&As[kk][m0 + 64];
      float4 bv = *(const float4*)&Bs[kk][n0];
      float av[8] = {a0.x, a0.y, a0.z, a0.w, a1.x, a1.y, a1.z, a1.w};
      float bw[4] = {bv.x, bv.y, bv.z, bv.w};
#pragma unroll
      for (int i = 0; i < 8; i++)
#pragma unroll
        for (int j = 0; j < 4; j++) acc[i][j] += av[i] * bw[j];
    }
    __syncthreads();
  }

  if (EPI == 3) {
#pragma unroll
    for (int j = 0; j < 4; j++) {
      float bia = bias[n0g + n0 + j];
      float cs = 0.f;
#pragma unroll
      for (int i = 0; i < 8; i++) {
        float v = acc[i][j] + bia;
        cs += (v > 0.f ? v : 0.f);
      }
      for (int off = 1; off < 16; off <<= 1) cs += __shfl_xor(cs, off);
      if ((tid & 15) == 0) atomicAdd(&meansum[b * Ntot + n0g + n0 + j], cs);
    }
    return;
  }

  float ss = 1.f, sb = 0.f;
  if (EPI == 2) { ss = star_scale[0]; sb = star_bias[0]; }
#pragma unroll
  for (int j = 0; j < 4; j++) {
    int n = n0g + n0 + j;
    float bia = (EPI == 1) ? bias[n] : 0.f;
    float* Cp = C + ((size_t)b * Ntot + n) * HW + hw0;
    float vv[8];
#pragma unroll
    for (int i = 0; i < 8; i++) {
      float v = acc[i][j];
      if (EPI == 1) { v += bia; v = v > 0.f ? v : 0.f; }
      if (EPI == 2) { v = v > 0.f ? v : 0.f; v = ss * v * v + sb; }
      vv[i] = v;
    }
    *(float4*)&Cp[m0]      = make_float4(vv[0], vv[1], vv[2], vv[3]);
    *(float4*)&Cp[m0 + 64] = make_float4(vv[4], vv[5], vv[6], vv[7]);
  }
}

// ---------------- sp_fc1 3x3 conv + relu + aggregate sums (lean implicit GEMM) ----------------
__global__ __launch_bounds__(256, 3) void conv3_gemm(
    const float* __restrict__ x, const float* __restrict__ w,
    const float* __restrict__ bias, float* __restrict__ agg)
{
  __shared__ float Xs[8][4][66];
  __shared__ __align__(16) float Ws2[8][64][12];
  const int tid = threadIdx.x;
  const int bx = blockIdx.x;
  const int o0 = blockIdx.y * 64;
  const int b  = blockIdx.z;
  const int ot = tid >> 5;
  const int mt = tid & 31;
  const int h0 = bx * 2;

  float acc[8][4];
#pragma unroll
  for (int o = 0; o < 8; o++)
#pragma unroll
    for (int p = 0; p < 4; p++) acc[o][p] = 0.f;

  for (int c0 = 0; c0 < DIMC; c0 += 8) {
#pragma unroll
    for (int i = 0; i < 9; i++) {
      int idx = i * 256 + tid;
      if (idx < 2112) {
        int c = idx / 264; int rem = idx - c * 264;
        int r = rem / 66;  int cc = rem - r * 66;
        int h = h0 + r - 1;
        int col = cc - 1;
        float v = 0.f;
        if (h >= 0 && h < 64 && col >= 0 && col < 64)
          v = x[((size_t)(b * DIMC + c0 + c)) * HW + h * 64 + col];
        Xs[c][r][cc] = v;
      }
    }
#pragma unroll
    for (int i = 0; i < 18; i++) {
      int idx = i * 256 + tid;
      int o = idx / 72; int k = idx - o * 72;
      int c = k / 9;    int t = k - c * 9;
      Ws2[c][o][t] = w[((size_t)(o0 + o) * DIMC + c0 + c) * 9 + t];
    }
    __syncthreads();

#pragma unroll
    for (int c = 0; c < 8; c++) {
      float win[4][4];
#pragma unroll
      for (int r = 0; r < 4; r++) {
        float2 a0 = *(const float2*)&Xs[c][r][2 * mt];
        float2 a1 = *(const float2*)&Xs[c][r][2 * mt + 2];
        win[r][0] = a0.x; win[r][1] = a0.y; win[r][2] = a1.x; win[r][3] = a1.y;
      }
#pragma unroll
      for (int o = 0; o < 8; o++) {
        float4 wv0 = *(const float4*)&Ws2[c][ot * 8 + o][0];
        float4 wv1 = *(const float4*)&Ws2[c][ot * 8 + o][4];
        float wv8  = Ws2[c][ot * 8 + o][8];
        float wv[9] = {wv0.x, wv0.y, wv0.z, wv0.w, wv1.x, wv1.y, wv1.z, wv1.w, wv8};
#pragma unroll
        for (int t = 0; t < 9; t++) {
          const int di = t / 3, dj = t % 3;
          acc[o][0] += win[0 + di][0 + dj] * wv[t];
          acc[o][1] += win[0 + di][1 + dj] * wv[t];
          acc[o][2] += win[1 + di][0 + dj] * wv[t];
          acc[o][3] += win[1 + di][1 + dj] * wv[t];
        }
      }
    }
    __syncthreads();
  }

#pragma unroll
  for (int o = 0; o < 8; o++) {
    int oo = o0 + ot * 8 + o;
    float bia = bias[oo];
    float v00 = fmaxf(acc[o][0] + bia, 0.f);
    float v01 = fmaxf(acc[o][1] + bia, 0.f);
    float v10 = fmaxf(acc[o][2] + bia, 0.f);
    float v11 = fmaxf(acc[o][3] + bia, 0.f);
    float* ag = &agg[((size_t)b * HSC + oo) * 9];

    float T = v00 + v01 + v10 + v11;
#pragma unroll
    for (int off = 16; off > 0; off >>= 1) T += __shfl_xor(T, off);
    if (mt == 0) atomicAdd(ag + 0, T);

    if (bx == 0) {
      float rs = v00 + v01;
#pragma unroll
      for (int off = 16; off > 0; off >>= 1) rs += __shfl_xor(rs, off);
      if (mt == 0) { atomicAdd(ag + 1, rs); atomicAdd(ag + 5, v00); }
      if (mt == 31) atomicAdd(ag + 6, v01);
    }
    if (bx == 31) {
      float rs = v10 + v11;
#pragma unroll
      for (int off = 16; off > 0; off >>= 1) rs += __shfl_xor(rs, off);
      if (mt == 0) { atomicAdd(ag + 2, rs); atomicAdd(ag + 7, v10); }
      if (mt == 31) atomicAdd(ag + 8, v11);
    }
    if (mt == 0)  atomicAdd(ag + 3, v00 + v10);
    if (mt == 31) atomicAdd(ag + 4, v01 + v11);
  }
}

// ---------------- aggregates -> 9 tap sums (already /4096) ----------------
__global__ void tap_compute(const float* __restrict__ agg, float* __restrict__ tap)
{
  int b = blockIdx.x; int c = threadIdx.x;
  const float* a = &agg[((size_t)b * HSC + c) * 9];
  float T = a[0], R0 = a[1], RH = a[2], C0 = a[3], CW = a[4];
  float s00 = a[5], s0W = a[6], sH0 = a[7], sHW = a[8];
  float* tp = &tap[((size_t)b * HSC + c) * 9];
#pragma unroll
  for (int i = 0; i < 3; i++)
#pragma unroll
    for (int j = 0; j < 3; j++) {
      int di = i - 1, dj = j - 1;
      float v = T;
      if (di == -1) v -= RH; else if (di == 1) v -= R0;
      if (dj == -1) v -= CW; else if (dj == 1) v -= C0;
      if (di == -1 && dj == -1) v += sHW;
      if (di == -1 && dj ==  1) v += sH0;
      if (di ==  1 && dj == -1) v += s0W;
      if (di ==  1 && dj ==  1) v += s00;
      tp[i * 3 + j] = v * (1.f / 4096.f);
    }
}

// ---------------- routing fc2 + softmax over NF ----------------
__global__ __launch_bounds__(256) void route_softmax(
    const float* __restrict__ meansum, const float* __restrict__ W,
    const float* __restrict__ bias, float* __restrict__ route)
{
  __shared__ float mv[HRC];
  int b = blockIdx.y;
  int m = blockIdx.x * 256 + threadIdx.x;
  mv[threadIdx.x] = meansum[b * HRC + threadIdx.x] * (1.f / 4096.f);
  __syncthreads();
  float l[4];
#pragma unroll
  for (int f = 0; f < 4; f++) {
    int o = f * MEDC + m;
    float accv = bias[o];
    const float* wr = &W[(size_t)o * HRC];
    for (int c = 0; c < HRC; c++) accv += wr[c] * mv[c];
    l[f] = accv;
  }
  float mx = fmaxf(fmaxf(l[0], l[1]), fmaxf(l[2], l[3]));
  float e[4], s = 0.f;
#pragma unroll
  for (int f = 0; f < 4; f++) { e[f] = expf(l[f] - mx); s += e[f]; }
  float inv = 1.f / s;
#pragma unroll
  for (int f = 0; f < 4; f++) route[((size_t)b * 4 + f) * MEDC + m] = e[f] * inv;
}

// ---------------- spatial routing fc2 (9-tap) + softmax ----------------
__global__ __launch_bounds__(256) void sproute_softmax(
    const float* __restrict__ tap, const float* __restrict__ W,
    const float* __restrict__ bias, float* __restrict__ sroute)
{
  __shared__ float tv[HSC * 9];
  int b = blockIdx.y;
  int m = blockIdx.x * 256 + threadIdx.x;
#pragma unroll
  for (int i = 0; i < 9; i++) {
    int idx = i * 256 + threadIdx.x;
    tv[idx] = tap[(size_t)b * HSC * 9 + idx];
  }
  __syncthreads();
  float l[4];
#pragma unroll
  for (int f = 0; f < 4; f++) {
    int o = f * MEDC + m;
    float accv = bias[o];
    const float* wr = &W[(size_t)o * HSC * 9];
    for (int ct = 0; ct < HSC * 9; ct++) accv += wr[ct] * tv[ct];
    l[f] = accv;
  }
  float mx = fmaxf(fmaxf(l[0], l[1]), fmaxf(l[2], l[3]));
  float e[4], s = 0.f;
#pragma unroll
  for (int f = 0; f < 4; f++) { e[f] = expf(l[f] - mx); s += e[f]; }
  float inv = 1.f / s;
#pragma unroll
  for (int f = 0; f < 4; f++) sroute[((size_t)b * 4 + f) * MEDC + m] = e[f] * inv;
}

// ---------------- radix-8x8 DFT helpers ----------------
// Forward (SGN=-1): X[k] = sum_n x[n] e^{-2pi i nk/8}; inverse (SGN=+1).
template<int SGN>
__device__ __forceinline__ void dft8(const float* xr, const float* xi, float* Xr, float* Xi) {
  const float S = (float)SGN;
  const float r = 0.70710678118654752440f;
  float t0r = xr[0] + xr[4], t0i = xi[0] + xi[4];
  float t1r = xr[0] - xr[4], t1i = xi[0] - xi[4];
  float t2r = xr[2] + xr[6], t2i = xi[2] + xi[6];
  float t3r = xr[2] - xr[6], t3i = xi[2] - xi[6];
  float E0r = t0r + t2r, E0i = t0i + t2i;
  float E2r = t0r - t2r, E2i = t0i - t2i;
  float E1r = t1r - S * t3i, E1i = t1i + S * t3r;
  float E3r = t1r + S * t3i, E3i = t1i - S * t3r;
  float u0r = xr[1] + xr[5], u0i = xi[1] + xi[5];
  float u1r = xr[1] - xr[5], u1i = xi[1] - xi[5];
  float u2r = xr[3] + xr[7], u2i = xi[3] + xi[7];
  float u3r = xr[3] - xr[7], u3i = xi[3] - xi[7];
  float O0r = u0r + u2r, O0i = u0i + u2i;
  float O2r = u0r - u2r, O2i = u0i - u2i;
  float O1r = u1r - S * u3i, O1i = u1i + S * u3r;
  float O3r = u1r + S * u3i, O3i = u1i - S * u3r;
  float p1r = r * (O1r - S * O1i), p1i = r * (S * O1r + O1i);
  float p2r = -S * O2i,            p2i = S * O2r;
  float p3r = -r * (O3r + S * O3i), p3i = r * (S * O3r - O3i);
  Xr[0] = E0r + O0r; Xi[0] = E0i + O0i;
  Xr[4] = E0r - O0r; Xi[4] = E0i - O0i;
  Xr[1] = E1r + p1r; Xi[1] = E1i + p1i;
  Xr[5] = E1r - p1r; Xi[5] = E1i - p1i;
  Xr[2] = E2r + p2r; Xi[2] = E2i + p2i;
  Xr[6] = E2r - p2r; Xi[6] = E2i - p2i;
  Xr[3] = E3r + p3r; Xi[3] = E3i + p3i;
  Xr[7] = E3r - p3r; Xi[7] = E3i - p3i;
}

// ---------------- radix-8x8 FFT filter + spatial gating, in-place on xp ----------------
__global__ __launch_bounds__(256) void fft_filter(
    float* __restrict__ xp, const float* __restrict__ route,
    const float* __restrict__ sroute, const float* __restrict__ cw,
    const float* __restrict__ spw)
{
  __shared__ float Fr[64][34], Fi[64][34];
  __shared__ float Cr[2176], Ci[2176];
  __shared__ float twc[64], tws[64];
  const int tid = threadIdx.x;
  const int blk = blockIdx.x;
  const int b = blk >> 10;
  const int m = blk & 1023;
  float* img = xp + (size_t)blk * HW;

  if (tid < 64) {
    float ang = (2.f * 3.14159265358979323846f / 64.f) * (float)tid;
    twc[tid] = cosf(ang); tws[tid] = sinf(ang);
  }
  float r4[4], s4[4];
#pragma unroll
  for (int f = 0; f < 4; f++) {
    r4[f] = route[((size_t)b * 4 + f) * MEDC + m] * (1.f / 4096.f);  // fold ortho norm
    s4[f] = sroute[((size_t)b * 4 + f) * MEDC + m];
  }
  __syncthreads();

  // ==== pass 1: row rfft (x[w] -> F[r][k], k=0..32), rows in 2 halves ====
#pragma unroll
  for (int half = 0; half < 2; half++) {
    {
      const int rh = tid & 31, n2 = tid >> 5;
      const int r = rh + half * 32;
      float xr[8], xi[8], Br[8], Bi[8];
#pragma unroll
      for (int n1 = 0; n1 < 8; n1++) { xr[n1] = img[r * 64 + 8 * n1 + n2]; xi[n1] = 0.f; }
      dft8<-1>(xr, xi, Br, Bi);
#pragma unroll
      for (int k1 = 0; k1 < 8; k1++) {
        int a = n2 * k1;
        float c = twc[a], s = tws[a];
        Cr[rh * 67 + k1 * 8 + n2] = Br[k1] * c + Bi[k1] * s;   // B * (c - i s)
        Ci[rh * 67 + k1 * 8 + n2] = Bi[k1] * c - Br[k1] * s;
      }
    }
    __syncthreads();
    {
      const int rh = tid & 31, k1 = tid >> 5;
      const int r = rh + half * 32;
      float xr[8], xi[8], Xr[8], Xi[8];
#pragma unroll
      for (int n2 = 0; n2 < 8; n2++) {
        xr[n2] = Cr[rh * 67 + k1 * 8 + n2];
        xi[n2] = Ci[rh * 67 + k1 * 8 + n2];
      }
      dft8<-1>(xr, xi, Xr, Xi);
      const int kmax = (k1 == 0) ? 5 : 4;   // keep k = k1+8*k2 <= 32
#pragma unroll
      for (int k2 = 0; k2 < 5; k2++) {
        if (k2 < kmax) {
          Fr[r][k1 + 8 * k2] = Xr[k2];
          Fi[r][k1 + 8 * k2] = Xi[k2];
        }
      }
    }
    __syncthreads();
  }

  // ==== pass 2: column fft over h + weight multiply -> F[kh][k] ====
  for (int t = tid; t < 264; t += 256) {
    const int k = t % 33, n2 = t / 33;
    float xr[8], xi[8], Br[8], Bi[8];
#pragma unroll
    for (int n1 = 0; n1 < 8; n1++) { xr[n1] = Fr[8 * n1 + n2][k]; xi[n1] = Fi[8 * n1 + n2][k]; }
    dft8<-1>(xr, xi, Br, Bi);
#pragma unroll
    for (int k1 = 0; k1 < 8; k1++) {
      int a = n2 * k1;
      float c = twc[a], s = tws[a];
      Cr[(k1 * 8 + n2) * 34 + k] = Br[k1] * c + Bi[k1] * s;
      Ci[(k1 * 8 + n2) * 34 + k] = Bi[k1] * c - Br[k1] * s;
    }
  }
  __syncthreads();
  for (int t = tid; t < 264; t += 256) {
    const int k = t % 33, k1 = t / 33;
    float xr[8], xi[8], Xr[8], Xi[8];
#pragma unroll
    for (int n2 = 0; n2 < 8; n2++) {
      xr[n2] = Cr[(k1 * 8 + n2) * 34 + k];
      xi[n2] = Ci[(k1 * 8 + n2) * 34 + k];
    }
    dft8<-1>(xr, xi, Xr, Xi);
#pragma unroll
    for (int k2 = 0; k2 < 8; k2++) {
      const int kh = k1 + 8 * k2;
      const float* cwp = &cw[(size_t)(kh * 33 + k) * 8];
      float wre = r4[0] * cwp[0] + r4[1] * cwp[2] + r4[2] * cwp[4] + r4[3] * cwp[6];
      float wim = r4[0] * cwp[1] + r4[1] * cwp[3] + r4[2] * cwp[5] + r4[3] * cwp[7];
      Fr[kh][k] = Xr[k2] * wre - Xi[k2] * wim;
      Fi[kh][k] = Xr[k2] * wim + Xi[k2] * wre;
    }
  }
  __syncthreads();

  // ==== pass 3: inverse column fft -> F[h][k] ====
  for (int t = tid; t < 264; t += 256) {
    const int k = t % 33, m2 = t / 33;
    float xr[8], xi[8], Br[8], Bi[8];
#pragma unroll
    for (int m1 = 0; m1 < 8; m1++) { xr[m1] = Fr[8 * m1 + m2][k]; xi[m1] = Fi[8 * m1 + m2][k]; }
    dft8<1>(xr, xi, Br, Bi);
#pragma unroll
    for (int h1 = 0; h1 < 8; h1++) {
      int a = m2 * h1;
      float c = twc[a], s = tws[a];
      Cr[(h1 * 8 + m2) * 34 + k] = Br[h1] * c - Bi[h1] * s;   // B * (c + i s)
      Ci[(h1 * 8 + m2) * 34 + k] = Bi[h1] * c + Br[h1] * s;
    }
  }
  __syncthreads();
  for (int t = tid; t < 264; t += 256) {
    const int k = t % 33, h1 = t / 33;
    float xr[8], xi[8], Xr[8], Xi[8];
#pragma unroll
    for (int m2 = 0; m2 < 8; m2++) {
      xr[m2] = Cr[(h1 * 8 + m2) * 34 + k];
      xi[m2] = Ci[(h1 * 8 + m2) * 34 + k];
    }
    dft8<1>(xr, xi, Xr, Xi);
#pragma unroll
    for (int h2 = 0; h2 < 8; h2++) {
      Fr[h1 + 8 * h2][k] = Xr[h2];
      Fi[h1 + 8 * h2][k] = Xi[h2];
    }
  }
  __syncthreads();

  // ==== pass 4: row irfft + spatial gating epilogue, rows in 2 halves ====
#pragma unroll
  for (int half = 0; half < 2; half++) {
    {
      const int rh = tid & 31, m2 = tid >> 5;
      const int r = rh + half * 32;
      float xr[8], xi[8], Br[8], Bi[8];
      if (m2 == 0) {
        xr[0] = Fr[r][0];  xi[0] = 0.f;
        xr[4] = Fr[r][32]; xi[4] = 0.f;
      } else {
        xr[0] = 2.f * Fr[r][m2]; xi[0] = 2.f * Fi[r][m2];
        xr[4] = 0.f; xi[4] = 0.f;
      }
#pragma unroll
      for (int m1 = 1; m1 < 4; m1++) {
        xr[m1] = 2.f * Fr[r][8 * m1 + m2];
        xi[m1] = 2.f * Fi[r][8 * m1 + m2];
      }
      xr[5] = 0.f; xi[5] = 0.f; xr[6] = 0.f; xi[6] = 0.f; xr[7] = 0.f; xi[7] = 0.f;
      dft8<1>(xr, xi, Br, Bi);
#pragma unroll
      for (int h1 = 0; h1 < 8; h1++) {
        int a = m2 * h1;
        float c = twc[a], s = tws[a];
        Cr[rh * 67 + h1 * 8 + m2] = Br[h1] * c - Bi[h1] * s;
        Ci[rh * 67 + h1 * 8 + m2] = Bi[h1] * c + Br[h1] * s;
      }
    }
    __syncthreads();
    {
      const int rh = tid & 31, h1 = tid >> 5;
      const int r = rh + half * 32;
      float xr[8], xi[8], Xr[8], Xi[8];
#pragma unroll
      for (int m2 = 0; m2 < 8; m2++) {
        xr[m2] = Cr[rh * 67 + h1 * 8 + m2];
        xi[m2] = Ci[rh * 67 + h1 * 8 + m2];
      }
      dft8<1>(xr, xi, Xr, Xi);
#pragma unroll
      for (int h2 = 0; h2 < 8; h2++) {
        const int w = h1 + 8 * h2;
        const int pix = r * 64 + w;
        float xv = img[pix];
        const float* sp = &spw[(size_t)pix * 4];
        float sw = s4[0] * sp[0] + s4[1] * sp[1] + s4[2] * sp[2] + s4[3] * sp[3];
        img[pix] = xv * sw + Xr[h2];   // Re part only (irfft)
      }
    }
    __syncthreads();
  }
}

extern "C" void kernel_launch(void* const* d_in, const int* in_sizes, int n_in,
                              void* d_out, int out_size, void* d_ws, size_t ws_size,
                              hipStream_t stream) {
  const float* x          = (const float*)d_in[0];
  const float* w_pw1      = (const float*)d_in[1];
  const float* w_pw2      = (const float*)d_in[2];
  const float* star_scale = (const float*)d_in[3];
  const float* star_bias  = (const float*)d_in[4];
  const float* rw1w = (const float*)d_in[5];
  const float* rw1b = (const float*)d_in[6];
  const float* rwcw = (const float*)d_in[7];
  const float* rwcb = (const float*)d_in[8];
  const float* rw2w = (const float*)d_in[9];
  const float* rw2b = (const float*)d_in[10];
  const float* sp1w = (const float*)d_in[11];
  const float* sp1b = (const float*)d_in[12];
  const float* sp2w = (const float*)d_in[13];
  const float* sp2b = (const float*)d_in[14];
  const float* cw   = (const float*)d_in[15];
  const float* spw  = (const float*)d_in[16];

  if (ws_size < WS_END * sizeof(float)) return;

  float* ws = (float*)d_ws;
  float* xp      = ws + XP_OFF;
  float* r1      = ws + XP_OFF;
  float* meansum = ws + MEAN_OFF;
  float* agg     = ws + AGG_OFF;
  float* tap     = ws + TAP_OFF;
  float* route   = ws + ROUTE_OFF;
  float* sr      = ws + SR_OFF;
  float* out = (float*)d_out;

  hipMemsetAsync(meansum, 0, (4096 + 36864) * sizeof(float), stream);

  // routing branch
  gemm_cm<1><<<dim3(32, 4, 16), 256, 0, stream>>>(x, rw1w, rw1b, r1, nullptr, nullptr, nullptr, DIMC, HRC);
  gemm_cm<3><<<dim3(32, 4, 16), 256, 0, stream>>>(r1, rwcw, rwcb, nullptr, meansum, nullptr, nullptr, HRC, HRC);
  route_softmax<<<dim3(4, 16), 256, 0, stream>>>(meansum, rw2w, rw2b, route);

  // spatial routing branch
  conv3_gemm<<<dim3(32, 4, 16), 256, 0, stream>>>(x, sp1w, sp1b, agg);
  tap_compute<<<16, 256, 0, stream>>>(agg, tap);
  sproute_softmax<<<dim3(4, 16), 256, 0, stream>>>(tap, sp2w, sp2b, sr);

  // main path
  gemm_cm<2><<<dim3(32, 16, 16), 256, 0, stream>>>(x, w_pw1, nullptr, xp, nullptr, star_scale, star_bias, DIMC, MEDC);
  fft_filter<<<16384, 256, 0, stream>>>(xp, route, sr, cw, spw);
  gemm_cm<0><<<dim3(32, 8, 16), 256, 0, stream>>>(xp, w_pw2, nullptr, out, nullptr, nullptr, nullptr, MEDC, DIMC);
}

// Round 5
// 3453.032 us; speedup vs baseline: 5.9427x; 1.5365x over previous
//
#include <hip/hip_runtime.h>

#define HW    4096
#define DIMC  512
#define MEDC  1024
#define HRC   256
#define HSC   256
#define NBATCH 16

typedef __attribute__((ext_vector_type(8))) short bf16x8;
typedef __attribute__((ext_vector_type(4))) float f32x4;

// ---------------- workspace layout (floats) ----------------
static const size_t XP_OFF    = 0;                         // xp region: 67.1M floats; unions below
static const size_t R1_OFF    = 0;                         // r1: 16.8M floats (routing mid)
static const size_t XT_OFF    = 16777216;                  // xT bf16: 33.5M elems = 16.8M floats
static const size_t WBF_OFF   = 33554432;                  // wbf bf16: 1.18M elems = 0.59M floats
static const size_t MEAN_OFF  = 67108864;                  // 4096
static const size_t AGG_OFF   = MEAN_OFF + 4096;           // 16*256*9
static const size_t TAP_OFF   = AGG_OFF + 36864;           // 16*256*9
static const size_t ROUTE_OFF = TAP_OFF + 36864;           // 16*4*1024
static const size_t SR_OFF    = ROUTE_OFF + 65536;         // 16*4*1024
static const size_t WS_END    = SR_OFF + 65536;

__device__ __forceinline__ unsigned short f2bf(float f) {
  unsigned u = __float_as_uint(f);
  unsigned r = (u + 0x7fffu + ((u >> 16) & 1u)) >> 16;
  return (unsigned short)r;
}

// ---------------- x [b][c][4096] f32 -> xT [b][pix][512] bf16 ----------------
__global__ __launch_bounds__(256) void xpose_bf16(
    const float* __restrict__ x, unsigned short* __restrict__ xT)
{
  __shared__ unsigned short T[32][33];
  const int tid = threadIdx.x;
  const int p0 = blockIdx.x * 32, c0 = blockIdx.y * 32, bb = blockIdx.z;
#pragma unroll
  for (int i = 0; i < 4; i++) {
    int idx = i * 256 + tid;
    int c_l = idx >> 5, p_l = idx & 31;
    T[c_l][p_l] = f2bf(x[((size_t)(bb * DIMC + c0 + c_l)) * HW + p0 + p_l]);
  }
  __syncthreads();
#pragma unroll
  for (int i = 0; i < 4; i++) {
    int idx = i * 256 + tid;
    int p_l = idx >> 5, c_l = idx & 31;
    xT[((size_t)bb * HW + p0 + p_l) * DIMC + c0 + c_l] = T[c_l][p_l];
  }
}

// ---------------- sp1w [o][c][9] f32 -> wbf [t][o][c] bf16 ----------------
__global__ __launch_bounds__(256) void wconv_bf16(
    const float* __restrict__ w, unsigned short* __restrict__ wbf)
{
  int idx = blockIdx.x * 256 + threadIdx.x;   // over 256*512
  if (idx < HSC * DIMC) {
#pragma unroll
    for (int t = 0; t < 9; t++)
      wbf[(size_t)t * (HSC * DIMC) + idx] = f2bf(w[(size_t)idx * 9 + t]);
  }
}

// ---------------- generic channel-major GEMM (fp32) ----------------
template<int EPI>
__global__ __launch_bounds__(256) void gemm_cm(
    const float* __restrict__ A, const float* __restrict__ W,
    const float* __restrict__ bias, float* __restrict__ C,
    float* __restrict__ meansum,
    const float* __restrict__ star_scale, const float* __restrict__ star_bias,
    int K, int Ntot)
{
  __shared__ __align__(16) float As[16][128];
  __shared__ __align__(16) float Bs[16][64];
  const int tid = threadIdx.x;
  const int hw0 = blockIdx.x * 128;
  const int n0g = blockIdx.y * 64;
  const int b   = blockIdx.z;
  const float* Ab = A + (size_t)b * K * HW + hw0;

  float acc[8][4];
#pragma unroll
  for (int i = 0; i < 8; i++)
#pragma unroll
    for (int j = 0; j < 4; j++) acc[i][j] = 0.f;

  const int m0 = (tid & 15) * 4;
  const int n0 = (tid >> 4) * 4;

  for (int k0 = 0; k0 < K; k0 += 16) {
#pragma unroll
    for (int i = 0; i < 8; i++) {
      int idx = i * 256 + tid;
      int kk = idx >> 7, mm = idx & 127;
      As[kk][mm] = Ab[(size_t)(k0 + kk) * HW + mm];
    }
#pragma unroll
    for (int i = 0; i < 4; i++) {
      int idx = i * 256 + tid;
      int kk = idx & 15, nn = idx >> 4;
      Bs[kk][nn] = W[(size_t)(n0g + nn) * K + k0 + kk];
    }
    __syncthreads();
#pragma unroll
    for (int kk = 0; kk < 16; kk++) {
      float4 a0 = *(const float4*)&As[kk][m0];
      float4 a1 = *(const float4*)&As[kk][m0 + 64];
      float4 bv = *(const float4*)&Bs[kk][n0];
      float av[8] = {a0.x, a0.y, a0.z, a0.w, a1.x, a1.y, a1.z, a1.w};
      float bw[4] = {bv.x, bv.y, bv.z, bv.w};
#pragma unroll
      for (int i = 0; i < 8; i++)
#pragma unroll
        for (int j = 0; j < 4; j++) acc[i][j] += av[i] * bw[j];
    }
    __syncthreads();
  }

  if (EPI == 3) {
#pragma unroll
    for (int j = 0; j < 4; j++) {
      float bia = bias[n0g + n0 + j];
      float cs = 0.f;
#pragma unroll
      for (int i = 0; i < 8; i++) {
        float v = acc[i][j] + bia;
        cs += (v > 0.f ? v : 0.f);
      }
      for (int off = 1; off < 16; off <<= 1) cs += __shfl_xor(cs, off);
      if ((tid & 15) == 0) atomicAdd(&meansum[b * Ntot + n0g + n0 + j], cs);
    }
    return;
  }

  float ss = 1.f, sb = 0.f;
  if (EPI == 2) { ss = star_scale[0]; sb = star_bias[0]; }
#pragma unroll
  for (int j = 0; j < 4; j++) {
    int n = n0g + n0 + j;
    float bia = (EPI == 1) ? bias[n] : 0.f;
    float* Cp = C + ((size_t)b * Ntot + n) * HW + hw0;
    float vv[8];
#pragma unroll
    for (int i = 0; i < 8; i++) {
      float v = acc[i][j];
      if (EPI == 1) { v += bia; v = v > 0.f ? v : 0.f; }
      if (EPI == 2) { v = v > 0.f ? v : 0.f; v = ss * v * v + sb; }
      vv[i] = v;
    }
    *(float4*)&Cp[m0]      = make_float4(vv[0], vv[1], vv[2], vv[3]);
    *(float4*)&Cp[m0 + 64] = make_float4(vv[4], vv[5], vv[6], vv[7]);
  }
}

// ---------------- sp_fc1 3x3 conv (bf16 MFMA implicit GEMM) + relu + aggregates ----------------
// Block: 2 image rows (128 pix) x 128 o. 4 waves: wave w -> row h0+(w>>1), o half (w&1)*64.
// K loop: 9 taps x 16 chunks of 32 channels. agg as before.
__global__ __launch_bounds__(256) void conv3_mfma(
    const unsigned short* __restrict__ xT, const unsigned short* __restrict__ wbf,
    const float* __restrict__ bias, float* __restrict__ agg)
{
  __shared__ __align__(16) unsigned short As[128 * 40];  // [pix][c pad40]
  __shared__ __align__(16) unsigned short Bs[128 * 40];  // [o][c pad40]
  const int tid = threadIdx.x;
  const int bx = blockIdx.x;            // 0..31 -> rows 2bx, 2bx+1
  const int n0g = blockIdx.y * 128;     // o tile
  const int bb = blockIdx.z;
  const int h0 = bx * 2;
  const int wid = tid >> 6;
  const int lane = tid & 63;
  const int lo = lane & 15, hi = lane >> 4;
  const int wm = wid >> 1;              // row within tile
  const int wn = wid & 1;               // o half

  f32x4 acc[4][4];
#pragma unroll
  for (int mi = 0; mi < 4; mi++)
#pragma unroll
    for (int ni = 0; ni < 4; ni++) acc[mi][ni] = (f32x4){0.f, 0.f, 0.f, 0.f};

  for (int s = 0; s < 144; s++) {
    const int t = s >> 4;
    const int c0 = (s & 15) * 32;
    const int di = t / 3 - 1, dj = t % 3 - 1;
    // stage A: 128 pix x 32 c (tap-shifted, masked)
#pragma unroll
    for (int it = 0; it < 2; it++) {
      int idx = it * 256 + tid;
      int pix = idx >> 2, co = (idx & 3) * 8;
      int h = h0 + (pix >> 6) + di;
      int col = (pix & 63) + dj;
      uint4 v = make_uint4(0u, 0u, 0u, 0u);
      if (h >= 0 && h < 64 && col >= 0 && col < 64)
        v = *(const uint4*)&xT[((size_t)bb * HW + h * 64 + col) * DIMC + c0 + co];
      *(uint4*)&As[pix * 40 + co] = v;
    }
    // stage B: 128 o x 32 c
#pragma unroll
    for (int it = 0; it < 2; it++) {
      int idx = it * 256 + tid;
      int o = idx >> 2, co = (idx & 3) * 8;
      uint4 v = *(const uint4*)&wbf[((size_t)t * (HSC * DIMC)) + (size_t)(n0g + o) * DIMC + c0 + co];
      *(uint4*)&Bs[o * 40 + co] = v;
    }
    __syncthreads();

    bf16x8 a[4], bfr[4];
#pragma unroll
    for (int mi = 0; mi < 4; mi++)
      a[mi] = *(const bf16x8*)&As[(wm * 64 + mi * 16 + lo) * 40 + hi * 8];
#pragma unroll
    for (int ni = 0; ni < 4; ni++)
      bfr[ni] = *(const bf16x8*)&Bs[(wn * 64 + ni * 16 + lo) * 40 + hi * 8];
#pragma unroll
    for (int mi = 0; mi < 4; mi++)
#pragma unroll
      for (int ni = 0; ni < 4; ni++)
        acc[mi][ni] = __builtin_amdgcn_mfma_f32_16x16x32_bf16(a[mi], bfr[ni], acc[mi][ni], 0, 0, 0);
    __syncthreads();
  }

  // epilogue: relu + aggregates. pix_local = mi*16 + hi*4 + r (col in row), o = n0g+wn*64+ni*16+lo
  const int h = h0 + wm;
#pragma unroll
  for (int ni = 0; ni < 4; ni++) {
    const int o = n0g + wn * 64 + ni * 16 + lo;
    const float bia = bias[o];
    float T = 0.f;
#pragma unroll
    for (int mi = 0; mi < 4; mi++)
#pragma unroll
      for (int r = 0; r < 4; r++)
        T += fmaxf(acc[mi][ni][r] + bia, 0.f);
    T += __shfl_xor(T, 16);
    T += __shfl_xor(T, 32);
    float* ag = &agg[((size_t)bb * HSC + o) * 9];
    if (hi == 0) {
      atomicAdd(ag + 0, T);
      if (h == 0)  atomicAdd(ag + 1, T);
      if (h == 63) atomicAdd(ag + 2, T);
      float c0v = fmaxf(acc[0][ni][0] + bia, 0.f);   // pix 0 (col 0)
      atomicAdd(ag + 3, c0v);
      if (h == 0)  atomicAdd(ag + 5, c0v);
      if (h == 63) atomicAdd(ag + 7, c0v);
    }
    if (hi == 3) {
      float cwv = fmaxf(acc[3][ni][3] + bia, 0.f);   // pix 63 (col 63)
      atomicAdd(ag + 4, cwv);
      if (h == 0)  atomicAdd(ag + 6, cwv);
      if (h == 63) atomicAdd(ag + 8, cwv);
    }
  }
}

// ---------------- aggregates -> 9 tap sums (already /4096) ----------------
__global__ void tap_compute(const float* __restrict__ agg, float* __restrict__ tap)
{
  int b = blockIdx.x; int c = threadIdx.x;
  const float* a = &agg[((size_t)b * HSC + c) * 9];
  float T = a[0], R0 = a[1], RH = a[2], C0 = a[3], CW = a[4];
  float s00 = a[5], s0W = a[6], sH0 = a[7], sHW = a[8];
  float* tp = &tap[((size_t)b * HSC + c) * 9];
#pragma unroll
  for (int i = 0; i < 3; i++)
#pragma unroll
    for (int j = 0; j < 3; j++) {
      int di = i - 1, dj = j - 1;
      float v = T;
      if (di == -1) v -= RH; else if (di == 1) v -= R0;
      if (dj == -1) v -= CW; else if (dj == 1) v -= C0;
      if (di == -1 && dj == -1) v += sHW;
      if (di == -1 && dj ==  1) v += sH0;
      if (di ==  1 && dj == -1) v += s0W;
      if (di ==  1 && dj ==  1) v += s00;
      tp[i * 3 + j] = v * (1.f / 4096.f);
    }
}

// ---------------- routing fc2 + softmax over NF ----------------
__global__ __launch_bounds__(256) void route_softmax(
    const float* __restrict__ meansum, const float* __restrict__ W,
    const float* __restrict__ bias, float* __restrict__ route)
{
  __shared__ float mv[HRC];
  int b = blockIdx.y;
  int m = blockIdx.x * 256 + threadIdx.x;
  mv[threadIdx.x] = meansum[b * HRC + threadIdx.x] * (1.f / 4096.f);
  __syncthreads();
  float l[4];
#pragma unroll
  for (int f = 0; f < 4; f++) {
    int o = f * MEDC + m;
    float accv = bias[o];
    const float* wr = &W[(size_t)o * HRC];
    for (int c = 0; c < HRC; c++) accv += wr[c] * mv[c];
    l[f] = accv;
  }
  float mx = fmaxf(fmaxf(l[0], l[1]), fmaxf(l[2], l[3]));
  float e[4], s = 0.f;
#pragma unroll
  for (int f = 0; f < 4; f++) { e[f] = expf(l[f] - mx); s += e[f]; }
  float inv = 1.f / s;
#pragma unroll
  for (int f = 0; f < 4; f++) route[((size_t)b * 4 + f) * MEDC + m] = e[f] * inv;
}

// ---------------- spatial routing fc2 (9-tap) + softmax ----------------
__global__ __launch_bounds__(256) void sproute_softmax(
    const float* __restrict__ tap, const float* __restrict__ W,
    const float* __restrict__ bias, float* __restrict__ sroute)
{
  __shared__ float tv[HSC * 9];
  int b = blockIdx.y;
  int m = blockIdx.x * 256 + threadIdx.x;
#pragma unroll
  for (int i = 0; i < 9; i++) {
    int idx = i * 256 + threadIdx.x;
    tv[idx] = tap[(size_t)b * HSC * 9 + idx];
  }
  __syncthreads();
  float l[4];
#pragma unroll
  for (int f = 0; f < 4; f++) {
    int o = f * MEDC + m;
    float accv = bias[o];
    const float* wr = &W[(size_t)o * HSC * 9];
    for (int ct = 0; ct < HSC * 9; ct++) accv += wr[ct] * tv[ct];
    l[f] = accv;
  }
  float mx = fmaxf(fmaxf(l[0], l[1]), fmaxf(l[2], l[3]));
  float e[4], s = 0.f;
#pragma unroll
  for (int f = 0; f < 4; f++) { e[f] = expf(l[f] - mx); s += e[f]; }
  float inv = 1.f / s;
#pragma unroll
  for (int f = 0; f < 4; f++) sroute[((size_t)b * 4 + f) * MEDC + m] = e[f] * inv;
}

// ---------------- radix-8x8 DFT helpers ----------------
template<int SGN>
__device__ __forceinline__ void dft8(const float* xr, const float* xi, float* Xr, float* Xi) {
  const float S = (float)SGN;
  const float r = 0.70710678118654752440f;
  float t0r = xr[0] + xr[4], t0i = xi[0] + xi[4];
  float t1r = xr[0] - xr[4], t1i = xi[0] - xi[4];
  float t2r = xr[2] + xr[6], t2i = xi[2] + xi[6];
  float t3r = xr[2] - xr[6], t3i = xi[2] - xi[6];
  float E0r = t0r + t2r, E0i = t0i + t2i;
  float E2r = t0r - t2r, E2i = t0i - t2i;
  float E1r = t1r - S * t3i, E1i = t1i + S * t3r;
  float E3r = t1r + S * t3i, E3i = t1i - S * t3r;
  float u0r = xr[1] + xr[5], u0i = xi[1] + xi[5];
  float u1r = xr[1] - xr[5], u1i = xi[1] - xi[5];
  float u2r = xr[3] + xr[7], u2i = xi[3] + xi[7];
  float u3r = xr[3] - xr[7], u3i = xi[3] - xi[7];
  float O0r = u0r + u2r, O0i = u0i + u2i;
  float O2r = u0r - u2r, O2i = u0i - u2i;
  float O1r = u1r - S * u3i, O1i = u1i + S * u3r;
  float O3r = u1r + S * u3i, O3i = u1i - S * u3r;
  float p1r = r * (O1r - S * O1i), p1i = r * (S * O1r + O1i);
  float p2r = -S * O2i,            p2i = S * O2r;
  float p3r = -r * (O3r + S * O3i), p3i = r * (S * O3r - O3i);
  Xr[0] = E0r + O0r; Xi[0] = E0i + O0i;
  Xr[4] = E0r - O0r; Xi[4] = E0i - O0i;
  Xr[1] = E1r + p1r; Xi[1] = E1i + p1i;
  Xr[5] = E1r - p1r; Xi[5] = E1i - p1i;
  Xr[2] = E2r + p2r; Xi[2] = E2i + p2i;
  Xr[6] = E2r - p2r; Xi[6] = E2i - p2i;
  Xr[3] = E3r + p3r; Xi[3] = E3i + p3i;
  Xr[7] = E3r - p3r; Xi[7] = E3i - p3i;
}

// ---------------- radix-8x8 FFT filter + spatial gating, in-place on xp ----------------
__global__ __launch_bounds__(256) void fft_filter(
    float* __restrict__ xp, const float* __restrict__ route,
    const float* __restrict__ sroute, const float* __restrict__ cw,
    const float* __restrict__ spw)
{
  __shared__ float Fr[64][34], Fi[64][34];
  __shared__ float Cr[2176], Ci[2176];
  __shared__ float twc[64], tws[64];
  const int tid = threadIdx.x;
  const int blk = blockIdx.x;
  const int b = blk >> 10;
  const int m = blk & 1023;
  float* img = xp + (size_t)blk * HW;

  if (tid < 64) {
    float ang = (2.f * 3.14159265358979323846f / 64.f) * (float)tid;
    twc[tid] = cosf(ang); tws[tid] = sinf(ang);
  }
  float r4[4], s4[4];
#pragma unroll
  for (int f = 0; f < 4; f++) {
    r4[f] = route[((size_t)b * 4 + f) * MEDC + m] * (1.f / 4096.f);
    s4[f] = sroute[((size_t)b * 4 + f) * MEDC + m];
  }
  __syncthreads();

#pragma unroll
  for (int half = 0; half < 2; half++) {
    {
      const int rh = tid & 31, n2 = tid >> 5;
      const int r = rh + half * 32;
      float xr[8], xi[8], Br[8], Bi[8];
#pragma unroll
      for (int n1 = 0; n1 < 8; n1++) { xr[n1] = img[r * 64 + 8 * n1 + n2]; xi[n1] = 0.f; }
      dft8<-1>(xr, xi, Br, Bi);
#pragma unroll
      for (int k1 = 0; k1 < 8; k1++) {
        int a = n2 * k1;
        float c = twc[a], s = tws[a];
        Cr[rh * 67 + k1 * 8 + n2] = Br[k1] * c + Bi[k1] * s;
        Ci[rh * 67 + k1 * 8 + n2] = Bi[k1] * c - Br[k1] * s;
      }
    }
    __syncthreads();
    {
      const int rh = tid & 31, k1 = tid >> 5;
      const int r = rh + half * 32;
      float xr[8], xi[8], Xr[8], Xi[8];
#pragma unroll
      for (int n2 = 0; n2 < 8; n2++) {
        xr[n2] = Cr[rh * 67 + k1 * 8 + n2];
        xi[n2] = Ci[rh * 67 + k1 * 8 + n2];
      }
      dft8<-1>(xr, xi, Xr, Xi);
      const int kmax = (k1 == 0) ? 5 : 4;
#pragma unroll
      for (int k2 = 0; k2 < 5; k2++) {
        if (k2 < kmax) {
          Fr[r][k1 + 8 * k2] = Xr[k2];
          Fi[r][k1 + 8 * k2] = Xi[k2];
        }
      }
    }
    __syncthreads();
  }

  for (int t = tid; t < 264; t += 256) {
    const int k = t % 33, n2 = t / 33;
    float xr[8], xi[8], Br[8], Bi[8];
#pragma unroll
    for (int n1 = 0; n1 < 8; n1++) { xr[n1] = Fr[8 * n1 + n2][k]; xi[n1] = Fi[8 * n1 + n2][k]; }
    dft8<-1>(xr, xi, Br, Bi);
#pragma unroll
    for (int k1 = 0; k1 < 8; k1++) {
      int a = n2 * k1;
      float c = twc[a], s = tws[a];
      Cr[(k1 * 8 + n2) * 34 + k] = Br[k1] * c + Bi[k1] * s;
      Ci[(k1 * 8 + n2) * 34 + k] = Bi[k1] * c - Br[k1] * s;
    }
  }
  __syncthreads();
  for (int t = tid; t < 264; t += 256) {
    const int k = t % 33, k1 = t / 33;
    float xr[8], xi[8], Xr[8], Xi[8];
#pragma unroll
    for (int n2 = 0; n2 < 8; n2++) {
      xr[n2] = Cr[(k1 * 8 + n2) * 34 + k];
      xi[n2] = Ci[(k1 * 8 + n2) * 34 + k];
    }
    dft8<-1>(xr, xi, Xr, Xi);
#pragma unroll
    for (int k2 = 0; k2 < 8; k2++) {
      const int kh = k1 + 8 * k2;
      const float* cwp = &cw[(size_t)(kh * 33 + k) * 8];
      float wre = r4[0] * cwp[0] + r4[1] * cwp[2] + r4[2] * cwp[4] + r4[3] * cwp[6];
      float wim = r4[0] * cwp[1] + r4[1] * cwp[3] + r4[2] * cwp[5] + r4[3] * cwp[7];
      Fr[kh][k] = Xr[k2] * wre - Xi[k2] * wim;
      Fi[kh][k] = Xr[k2] * wim + Xi[k2] * wre;
    }
  }
  __syncthreads();

  for (int t = tid; t < 264; t += 256) {
    const int k = t % 33, m2 = t / 33;
    float xr[8], xi[8], Br[8], Bi[8];
#pragma unroll
    for (int m1 = 0; m1 < 8; m1++) { xr[m1] = Fr[8 * m1 + m2][k]; xi[m1] = Fi[8 * m1 + m2][k]; }
    dft8<1>(xr, xi, Br, Bi);
#pragma unroll
    for (int h1 = 0; h1 < 8; h1++) {
      int a = m2 * h1;
      float c = twc[a], s = tws[a];
      Cr[(h1 * 8 + m2) * 34 + k] = Br[h1] * c - Bi[h1] * s;
      Ci[(h1 * 8 + m2) * 34 + k] = Bi[h1] * c + Br[h1] * s;
    }
  }
  __syncthreads();
  for (int t = tid; t < 264; t += 256) {
    const int k = t % 33, h1 = t / 33;
    float xr[8], xi[8], Xr[8], Xi[8];
#pragma unroll
    for (int m2 = 0; m2 < 8; m2++) {
      xr[m2] = Cr[(h1 * 8 + m2) * 34 + k];
      xi[m2] = Ci[(h1 * 8 + m2) * 34 + k];
    }
    dft8<1>(xr, xi, Xr, Xi);
#pragma unroll
    for (int h2 = 0; h2 < 8; h2++) {
      Fr[h1 + 8 * h2][k] = Xr[h2];
      Fi[h1 + 8 * h2][k] = Xi[h2];
    }
  }
  __syncthreads();

#pragma unroll
  for (int half = 0; half < 2; half++) {
    {
      const int rh = tid & 31, m2 = tid >> 5;
      const int r = rh + half * 32;
      float xr[8], xi[8], Br[8], Bi[8];
      if (m2 == 0) {
        xr[0] = Fr[r][0];  xi[0] = 0.f;
        xr[4] = Fr[r][32]; xi[4] = 0.f;
      } else {
        xr[0] = 2.f * Fr[r][m2]; xi[0] = 2.f * Fi[r][m2];
        xr[4] = 0.f; xi[4] = 0.f;
      }
#pragma unroll
      for (int m1 = 1; m1 < 4; m1++) {
        xr[m1] = 2.f * Fr[r][8 * m1 + m2];
        xi[m1] = 2.f * Fi[r][8 * m1 + m2];
      }
      xr[5] = 0.f; xi[5] = 0.f; xr[6] = 0.f; xi[6] = 0.f; xr[7] = 0.f; xi[7] = 0.f;
      dft8<1>(xr, xi, Br, Bi);
#pragma unroll
      for (int h1 = 0; h1 < 8; h1++) {
        int a = m2 * h1;
        float c = twc[a], s = tws[a];
        Cr[rh * 67 + h1 * 8 + m2] = Br[h1] * c - Bi[h1] * s;
        Ci[rh * 67 + h1 * 8 + m2] = Bi[h1] * c + Br[h1] * s;
      }
    }
    __syncthreads();
    {
      const int rh = tid & 31, h1 = tid >> 5;
      const int r = rh + half * 32;
      float xr[8], xi[8], Xr[8], Xi[8];
#pragma unroll
      for (int m2 = 0; m2 < 8; m2++) {
        xr[m2] = Cr[rh * 67 + h1 * 8 + m2];
        xi[m2] = Ci[rh * 67 + h1 * 8 + m2];
      }
      dft8<1>(xr, xi, Xr, Xi);
#pragma unroll
      for (int h2 = 0; h2 < 8; h2++) {
        const int w = h1 + 8 * h2;
        const int pix = r * 64 + w;
        float xv = img[pix];
        const float* sp = &spw[(size_t)pix * 4];
        float sw = s4[0] * sp[0] + s4[1] * sp[1] + s4[2] * sp[2] + s4[3] * sp[3];
        img[pix] = xv * sw + Xr[h2];
      }
    }
    __syncthreads();
  }
}

extern "C" void kernel_launch(void* const* d_in, const int* in_sizes, int n_in,
                              void* d_out, int out_size, void* d_ws, size_t ws_size,
                              hipStream_t stream) {
  const float* x          = (const float*)d_in[0];
  const float* w_pw1      = (const float*)d_in[1];
  const float* w_pw2      = (const float*)d_in[2];
  const float* star_scale = (const float*)d_in[3];
  const float* star_bias  = (const float*)d_in[4];
  const float* rw1w = (const float*)d_in[5];
  const float* rw1b = (const float*)d_in[6];
  const float* rwcw = (const float*)d_in[7];
  const float* rwcb = (const float*)d_in[8];
  const float* rw2w = (const float*)d_in[9];
  const float* rw2b = (const float*)d_in[10];
  const float* sp1w = (const float*)d_in[11];
  const float* sp1b = (const float*)d_in[12];
  const float* sp2w = (const float*)d_in[13];
  const float* sp2b = (const float*)d_in[14];
  const float* cw   = (const float*)d_in[15];
  const float* spw  = (const float*)d_in[16];

  if (ws_size < WS_END * sizeof(float)) return;

  float* ws = (float*)d_ws;
  float* xp      = ws + XP_OFF;
  float* r1      = ws + R1_OFF;
  unsigned short* xT  = (unsigned short*)(ws + XT_OFF);
  unsigned short* wbf = (unsigned short*)(ws + WBF_OFF);
  float* meansum = ws + MEAN_OFF;
  float* agg     = ws + AGG_OFF;
  float* tap     = ws + TAP_OFF;
  float* route   = ws + ROUTE_OFF;
  float* sr      = ws + SR_OFF;
  float* out = (float*)d_out;

  hipMemsetAsync(meansum, 0, (4096 + 36864) * sizeof(float), stream);

  // bf16 prep for conv
  xpose_bf16<<<dim3(128, 16, 16), 256, 0, stream>>>(x, xT);
  wconv_bf16<<<512, 256, 0, stream>>>(sp1w, wbf);

  // routing branch
  gemm_cm<1><<<dim3(32, 4, 16), 256, 0, stream>>>(x, rw1w, rw1b, r1, nullptr, nullptr, nullptr, DIMC, HRC);
  gemm_cm<3><<<dim3(32, 4, 16), 256, 0, stream>>>(r1, rwcw, rwcb, nullptr, meansum, nullptr, nullptr, HRC, HRC);
  route_softmax<<<dim3(4, 16), 256, 0, stream>>>(meansum, rw2w, rw2b, route);

  // spatial routing branch (bf16 MFMA conv)
  conv3_mfma<<<dim3(32, 2, 16), 256, 0, stream>>>(xT, wbf, sp1b, agg);
  tap_compute<<<16, 256, 0, stream>>>(agg, tap);
  sproute_softmax<<<dim3(4, 16), 256, 0, stream>>>(tap, sp2w, sp2b, sr);

  // main path
  gemm_cm<2><<<dim3(32, 16, 16), 256, 0, stream>>>(x, w_pw1, nullptr, xp, nullptr, star_scale, star_bias, DIMC, MEDC);
  fft_filter<<<16384, 256, 0, stream>>>(xp, route, sr, cw, spw);
  gemm_cm<0><<<dim3(32, 8, 16), 256, 0, stream>>>(xp, w_pw2, nullptr, out, nullptr, nullptr, nullptr, MEDC, DIMC);
}

// Round 6
// 1727.186 us; speedup vs baseline: 11.8808x; 1.9992x over previous
//
#include <hip/hip_runtime.h>

#define HW    4096
#define DIMC  512
#define MEDC  1024
#define HRC   256
#define HSC   256
#define NBATCH 16

typedef __attribute__((ext_vector_type(8))) short bf16x8;
typedef __attribute__((ext_vector_type(4))) float f32x4;

// ---------------- workspace layout (floats) ----------------
// xp region [0, 67108864) f32; overlapped (dead before pw1 writes xp):
static const size_t R1_OFF    = 0;                 // r1 bf16 [16][4096][256]  -> 8388608 floats
static const size_t XT_OFF    = 8388608;           // xT bf16 [16][4096][512]  -> 16777216 floats
static const size_t WCONV_OFF = 25165824;          // conv w bf16 [9][256][512]-> 589824 floats
static const size_t WR1_OFF   = 25755648;          // rw1 w bf16 [256][512]    -> 65536 floats
static const size_t WRC_OFF   = 25821184;          // rwc w bf16 [256][256]    -> 32768 floats
static const size_t XP_OFF    = 0;                 // xp f32 [16][1024][4096]
// outside xp region:
static const size_t WB1_OFF   = 67108864;          // pw1 w bf16 [1024][512]   -> 262144 floats
static const size_t WB2_OFF   = 67371008;          // pw2 w bf16 [512][1024]   -> 262144 floats
static const size_t MEAN_OFF  = 67633152;          // 4096
static const size_t AGG_OFF   = MEAN_OFF + 4096;   // 36864
static const size_t TAP_OFF   = AGG_OFF + 36864;   // 36864
static const size_t ROUTE_OFF = TAP_OFF + 36864;   // 65536
static const size_t SR_OFF    = ROUTE_OFF + 65536; // 65536
static const size_t WS_END    = SR_OFF + 65536;

__device__ __forceinline__ unsigned short f2bf(float f) {
  unsigned u = __float_as_uint(f);
  unsigned r = (u + 0x7fffu + ((u >> 16) & 1u)) >> 16;
  return (unsigned short)r;
}

// ---------------- generic f32 -> bf16 elementwise ----------------
__global__ __launch_bounds__(256) void cvt_bf16(
    const float* __restrict__ src, unsigned short* __restrict__ dst, int n)
{
  int i = blockIdx.x * 256 + threadIdx.x;
  if (i < n) dst[i] = f2bf(src[i]);
}

// ---------------- x [b][c][4096] f32 -> xT [b][pix][512] bf16 ----------------
__global__ __launch_bounds__(256) void xpose_bf16(
    const float* __restrict__ x, unsigned short* __restrict__ xT)
{
  __shared__ unsigned short T[32][33];
  const int tid = threadIdx.x;
  const int p0 = blockIdx.x * 32, c0 = blockIdx.y * 32, bb = blockIdx.z;
#pragma unroll
  for (int i = 0; i < 4; i++) {
    int idx = i * 256 + tid;
    int c_l = idx >> 5, p_l = idx & 31;
    T[c_l][p_l] = f2bf(x[((size_t)(bb * DIMC + c0 + c_l)) * HW + p0 + p_l]);
  }
  __syncthreads();
#pragma unroll
  for (int i = 0; i < 4; i++) {
    int idx = i * 256 + tid;
    int p_l = idx >> 5, c_l = idx & 31;
    xT[((size_t)bb * HW + p0 + p_l) * DIMC + c0 + c_l] = T[c_l][p_l];
  }
}

// ---------------- sp1w [o][c][9] f32 -> wconv [t][o][c] bf16 ----------------
__global__ __launch_bounds__(256) void wconv_bf16(
    const float* __restrict__ w, unsigned short* __restrict__ wbf)
{
  int idx = blockIdx.x * 256 + threadIdx.x;
  if (idx < HSC * DIMC) {
#pragma unroll
    for (int t = 0; t < 9; t++)
      wbf[(size_t)t * (HSC * DIMC) + idx] = f2bf(w[(size_t)idx * 9 + t]);
  }
}

// ---------------- bf16 MFMA GEMM, 128 pix x 128 n tile, 4 waves ----------------
// ASRC 0: Aptr = ushort [B][4096][K] (pixel-major bf16)
// ASRC 1: Aptr = float  [B][K][4096] (channel-major f32, cvt on stage)
// EPI 0: plain        -> Cf [B][Ntot][4096] f32
// EPI 1: bias+relu    -> Cb [B][4096][Ntot] bf16
// EPI 2: StarReLU     -> Cf [B][Ntot][4096] f32
// EPI 3: bias+relu -> column meansum atomics (no C write)
template<int EPI, int ASRC>
__global__ __launch_bounds__(256) void gemm_bf16(
    const void* __restrict__ Aptr, const unsigned short* __restrict__ Wb,
    const float* __restrict__ bias, float* __restrict__ Cf,
    unsigned short* __restrict__ Cb, float* __restrict__ meansum,
    const float* __restrict__ star_scale, const float* __restrict__ star_bias,
    int K, int Ntot)
{
  __shared__ __align__(16) unsigned short As[128 * 40];
  __shared__ __align__(16) unsigned short Bs[128 * 40];
  const int tid = threadIdx.x;
  const int pix0 = blockIdx.x * 128;
  const int n0g = blockIdx.y * 128;
  const int bb = blockIdx.z;
  const int wid = tid >> 6, lane = tid & 63;
  const int lo = lane & 15, hi = lane >> 4;
  const int wm = wid >> 1, wn = wid & 1;

  f32x4 acc[4][4];
#pragma unroll
  for (int mi = 0; mi < 4; mi++)
#pragma unroll
    for (int ni = 0; ni < 4; ni++) acc[mi][ni] = (f32x4){0.f, 0.f, 0.f, 0.f};

  const int nsteps = K >> 5;
  for (int s = 0; s < nsteps; s++) {
    const int c0 = s * 32;
    if (ASRC == 0) {
      const unsigned short* AT = (const unsigned short*)Aptr;
#pragma unroll
      for (int it = 0; it < 2; it++) {
        int idx = it * 256 + tid;
        int p = idx >> 2, co = (idx & 3) * 8;
        uint4 v = *(const uint4*)&AT[((size_t)bb * HW + pix0 + p) * K + c0 + co];
        *(uint4*)&As[p * 40 + co] = v;
      }
    } else {
      const float* Af = (const float*)Aptr;
#pragma unroll
      for (int it = 0; it < 16; it++) {
        int idx = it * 256 + tid;
        int k_l = idx >> 7, p_l = idx & 127;
        float v = Af[((size_t)bb * K + c0 + k_l) * HW + pix0 + p_l];
        As[p_l * 40 + k_l] = f2bf(v);
      }
    }
#pragma unroll
    for (int it = 0; it < 2; it++) {
      int idx = it * 256 + tid;
      int o = idx >> 2, co = (idx & 3) * 8;
      uint4 v = *(const uint4*)&Wb[(size_t)(n0g + o) * K + c0 + co];
      *(uint4*)&Bs[o * 40 + co] = v;
    }
    __syncthreads();

    bf16x8 a[4], bq[4];
#pragma unroll
    for (int mi = 0; mi < 4; mi++)
      a[mi] = *(const bf16x8*)&As[(wm * 64 + mi * 16 + lo) * 40 + hi * 8];
#pragma unroll
    for (int ni = 0; ni < 4; ni++)
      bq[ni] = *(const bf16x8*)&Bs[(wn * 64 + ni * 16 + lo) * 40 + hi * 8];
#pragma unroll
    for (int mi = 0; mi < 4; mi++)
#pragma unroll
      for (int ni = 0; ni < 4; ni++)
        acc[mi][ni] = __builtin_amdgcn_mfma_f32_16x16x32_bf16(a[mi], bq[ni], acc[mi][ni], 0, 0, 0);
    __syncthreads();
  }

  if (EPI == 3) {
#pragma unroll
    for (int ni = 0; ni < 4; ni++) {
      const int n = n0g + wn * 64 + ni * 16 + lo;
      const float bia = bias[n];
      float T = 0.f;
#pragma unroll
      for (int mi = 0; mi < 4; mi++)
#pragma unroll
        for (int r = 0; r < 4; r++)
          T += fmaxf(acc[mi][ni][r] + bia, 0.f);
      T += __shfl_xor(T, 16);
      T += __shfl_xor(T, 32);
      if (hi == 0) atomicAdd(&meansum[bb * Ntot + n], T);
    }
    return;
  }

  if (EPI == 1) {
#pragma unroll
    for (int ni = 0; ni < 4; ni++) {
      const int n = n0g + wn * 64 + ni * 16 + lo;
      const float bia = bias[n];
#pragma unroll
      for (int mi = 0; mi < 4; mi++)
#pragma unroll
        for (int r = 0; r < 4; r++) {
          const int pix = pix0 + wm * 64 + mi * 16 + hi * 4 + r;
          Cb[((size_t)bb * HW + pix) * Ntot + n] = f2bf(fmaxf(acc[mi][ni][r] + bia, 0.f));
        }
    }
    return;
  }

  float ss = 1.f, sb = 0.f;
  if (EPI == 2) { ss = star_scale[0]; sb = star_bias[0]; }
#pragma unroll
  for (int ni = 0; ni < 4; ni++) {
    const int n = n0g + wn * 64 + ni * 16 + lo;
#pragma unroll
    for (int mi = 0; mi < 4; mi++) {
      const int pixb = pix0 + wm * 64 + mi * 16 + hi * 4;
      float4 v;
      float* vv = (float*)&v;
#pragma unroll
      for (int r = 0; r < 4; r++) {
        float t = acc[mi][ni][r];
        if (EPI == 2) { t = fmaxf(t, 0.f); t = ss * t * t + sb; }
        vv[r] = t;
      }
      *(float4*)&Cf[((size_t)bb * Ntot + n) * HW + pixb] = v;
    }
  }
}

// ---------------- sp_fc1 3x3 conv (bf16 MFMA implicit GEMM) + relu + aggregates ----------------
__global__ __launch_bounds__(256) void conv3_mfma(
    const unsigned short* __restrict__ xT, const unsigned short* __restrict__ wbf,
    const float* __restrict__ bias, float* __restrict__ agg)
{
  __shared__ __align__(16) unsigned short As[128 * 40];
  __shared__ __align__(16) unsigned short Bs[128 * 40];
  const int tid = threadIdx.x;
  const int bx = blockIdx.x;
  const int n0g = blockIdx.y * 128;
  const int bb = blockIdx.z;
  const int h0 = bx * 2;
  const int wid = tid >> 6;
  const int lane = tid & 63;
  const int lo = lane & 15, hi = lane >> 4;
  const int wm = wid >> 1;
  const int wn = wid & 1;

  f32x4 acc[4][4];
#pragma unroll
  for (int mi = 0; mi < 4; mi++)
#pragma unroll
    for (int ni = 0; ni < 4; ni++) acc[mi][ni] = (f32x4){0.f, 0.f, 0.f, 0.f};

  for (int s = 0; s < 144; s++) {
    const int t = s >> 4;
    const int c0 = (s & 15) * 32;
    const int di = t / 3 - 1, dj = t % 3 - 1;
#pragma unroll
    for (int it = 0; it < 2; it++) {
      int idx = it * 256 + tid;
      int pix = idx >> 2, co = (idx & 3) * 8;
      int h = h0 + (pix >> 6) + di;
      int col = (pix & 63) + dj;
      uint4 v = make_uint4(0u, 0u, 0u, 0u);
      if (h >= 0 && h < 64 && col >= 0 && col < 64)
        v = *(const uint4*)&xT[((size_t)bb * HW + h * 64 + col) * DIMC + c0 + co];
      *(uint4*)&As[pix * 40 + co] = v;
    }
#pragma unroll
    for (int it = 0; it < 2; it++) {
      int idx = it * 256 + tid;
      int o = idx >> 2, co = (idx & 3) * 8;
      uint4 v = *(const uint4*)&wbf[((size_t)t * (HSC * DIMC)) + (size_t)(n0g + o) * DIMC + c0 + co];
      *(uint4*)&Bs[o * 40 + co] = v;
    }
    __syncthreads();

    bf16x8 a[4], bfr[4];
#pragma unroll
    for (int mi = 0; mi < 4; mi++)
      a[mi] = *(const bf16x8*)&As[(wm * 64 + mi * 16 + lo) * 40 + hi * 8];
#pragma unroll
    for (int ni = 0; ni < 4; ni++)
      bfr[ni] = *(const bf16x8*)&Bs[(wn * 64 + ni * 16 + lo) * 40 + hi * 8];
#pragma unroll
    for (int mi = 0; mi < 4; mi++)
#pragma unroll
      for (int ni = 0; ni < 4; ni++)
        acc[mi][ni] = __builtin_amdgcn_mfma_f32_16x16x32_bf16(a[mi], bfr[ni], acc[mi][ni], 0, 0, 0);
    __syncthreads();
  }

  const int h = h0 + wm;
#pragma unroll
  for (int ni = 0; ni < 4; ni++) {
    const int o = n0g + wn * 64 + ni * 16 + lo;
    const float bia = bias[o];
    float T = 0.f;
#pragma unroll
    for (int mi = 0; mi < 4; mi++)
#pragma unroll
      for (int r = 0; r < 4; r++)
        T += fmaxf(acc[mi][ni][r] + bia, 0.f);
    T += __shfl_xor(T, 16);
    T += __shfl_xor(T, 32);
    float* ag = &agg[((size_t)bb * HSC + o) * 9];
    if (hi == 0) {
      atomicAdd(ag + 0, T);
      if (h == 0)  atomicAdd(ag + 1, T);
      if (h == 63) atomicAdd(ag + 2, T);
      float c0v = fmaxf(acc[0][ni][0] + bia, 0.f);
      atomicAdd(ag + 3, c0v);
      if (h == 0)  atomicAdd(ag + 5, c0v);
      if (h == 63) atomicAdd(ag + 7, c0v);
    }
    if (hi == 3) {
      float cwv = fmaxf(acc[3][ni][3] + bia, 0.f);
      atomicAdd(ag + 4, cwv);
      if (h == 0)  atomicAdd(ag + 6, cwv);
      if (h == 63) atomicAdd(ag + 8, cwv);
    }
  }
}

// ---------------- aggregates -> 9 tap sums ----------------
__global__ void tap_compute(const float* __restrict__ agg, float* __restrict__ tap)
{
  int b = blockIdx.x; int c = threadIdx.x;
  const float* a = &agg[((size_t)b * HSC + c) * 9];
  float T = a[0], R0 = a[1], RH = a[2], C0 = a[3], CW = a[4];
  float s00 = a[5], s0W = a[6], sH0 = a[7], sHW = a[8];
  float* tp = &tap[((size_t)b * HSC + c) * 9];
#pragma unroll
  for (int i = 0; i < 3; i++)
#pragma unroll
    for (int j = 0; j < 3; j++) {
      int di = i - 1, dj = j - 1;
      float v = T;
      if (di == -1) v -= RH; else if (di == 1) v -= R0;
      if (dj == -1) v -= CW; else if (dj == 1) v -= C0;
      if (di == -1 && dj == -1) v += sHW;
      if (di == -1 && dj ==  1) v += sH0;
      if (di ==  1 && dj == -1) v += s0W;
      if (di ==  1 && dj ==  1) v += s00;
      tp[i * 3 + j] = v * (1.f / 4096.f);
    }
}

// ---------------- routing fc2 + softmax over NF ----------------
__global__ __launch_bounds__(256) void route_softmax(
    const float* __restrict__ meansum, const float* __restrict__ W,
    const float* __restrict__ bias, float* __restrict__ route)
{
  __shared__ float mv[HRC];
  int b = blockIdx.y;
  int m = blockIdx.x * 256 + threadIdx.x;
  mv[threadIdx.x] = meansum[b * HRC + threadIdx.x] * (1.f / 4096.f);
  __syncthreads();
  float l[4];
#pragma unroll
  for (int f = 0; f < 4; f++) {
    int o = f * MEDC + m;
    float accv = bias[o];
    const float* wr = &W[(size_t)o * HRC];
    for (int c = 0; c < HRC; c++) accv += wr[c] * mv[c];
    l[f] = accv;
  }
  float mx = fmaxf(fmaxf(l[0], l[1]), fmaxf(l[2], l[3]));
  float e[4], s = 0.f;
#pragma unroll
  for (int f = 0; f < 4; f++) { e[f] = expf(l[f] - mx); s += e[f]; }
  float inv = 1.f / s;
#pragma unroll
  for (int f = 0; f < 4; f++) route[((size_t)b * 4 + f) * MEDC + m] = e[f] * inv;
}

// ---------------- spatial routing fc2 (9-tap) + softmax ----------------
__global__ __launch_bounds__(256) void sproute_softmax(
    const float* __restrict__ tap, const float* __restrict__ W,
    const float* __restrict__ bias, float* __restrict__ sroute)
{
  __shared__ float tv[HSC * 9];
  int b = blockIdx.y;
  int m = blockIdx.x * 256 + threadIdx.x;
#pragma unroll
  for (int i = 0; i < 9; i++) {
    int idx = i * 256 + threadIdx.x;
    tv[idx] = tap[(size_t)b * HSC * 9 + idx];
  }
  __syncthreads();
  float l[4];
#pragma unroll
  for (int f = 0; f < 4; f++) {
    int o = f * MEDC + m;
    float accv = bias[o];
    const float* wr = &W[(size_t)o * HSC * 9];
    for (int ct = 0; ct < HSC * 9; ct++) accv += wr[ct] * tv[ct];
    l[f] = accv;
  }
  float mx = fmaxf(fmaxf(l[0], l[1]), fmaxf(l[2], l[3]));
  float e[4], s = 0.f;
#pragma unroll
  for (int f = 0; f < 4; f++) { e[f] = expf(l[f] - mx); s += e[f]; }
  float inv = 1.f / s;
#pragma unroll
  for (int f = 0; f < 4; f++) sroute[((size_t)b * 4 + f) * MEDC + m] = e[f] * inv;
}

// ---------------- radix-8x8 DFT helpers ----------------
template<int SGN>
__device__ __forceinline__ void dft8(const float* xr, const float* xi, float* Xr, float* Xi) {
  const float S = (float)SGN;
  const float r = 0.70710678118654752440f;
  float t0r = xr[0] + xr[4], t0i = xi[0] + xi[4];
  float t1r = xr[0] - xr[4], t1i = xi[0] - xi[4];
  float t2r = xr[2] + xr[6], t2i = xi[2] + xi[6];
  float t3r = xr[2] - xr[6], t3i = xi[2] - xi[6];
  float E0r = t0r + t2r, E0i = t0i + t2i;
  float E2r = t0r - t2r, E2i = t0i - t2i;
  float E1r = t1r - S * t3i, E1i = t1i + S * t3r;
  float E3r = t1r + S * t3i, E3i = t1i - S * t3r;
  float u0r = xr[1] + xr[5], u0i = xi[1] + xi[5];
  float u1r = xr[1] - xr[5], u1i = xi[1] - xi[5];
  float u2r = xr[3] + xr[7], u2i = xi[3] + xi[7];
  float u3r = xr[3] - xr[7], u3i = xi[3] - xi[7];
  float O0r = u0r + u2r, O0i = u0i + u2i;
  float O2r = u0r - u2r, O2i = u0i - u2i;
  float O1r = u1r - S * u3i, O1i = u1i + S * u3r;
  float O3r = u1r + S * u3i, O3i = u1i - S * u3r;
  float p1r = r * (O1r - S * O1i), p1i = r * (S * O1r + O1i);
  float p2r = -S * O2i,            p2i = S * O2r;
  float p3r = -r * (O3r + S * O3i), p3i = r * (S * O3r - O3i);
  Xr[0] = E0r + O0r; Xi[0] = E0i + O0i;
  Xr[4] = E0r - O0r; Xi[4] = E0i - O0i;
  Xr[1] = E1r + p1r; Xi[1] = E1i + p1i;
  Xr[5] = E1r - p1r; Xi[5] = E1i - p1i;
  Xr[2] = E2r + p2r; Xi[2] = E2i + p2i;
  Xr[6] = E2r - p2r; Xi[6] = E2i - p2i;
  Xr[3] = E3r + p3r; Xi[3] = E3i + p3i;
  Xr[7] = E3r - p3r; Xi[7] = E3i - p3i;
}

// ---------------- radix-8x8 FFT filter + spatial gating, in-place on xp ----------------
__global__ __launch_bounds__(256) void fft_filter(
    float* __restrict__ xp, const float* __restrict__ route,
    const float* __restrict__ sroute, const float* __restrict__ cw,
    const float* __restrict__ spw)
{
  __shared__ float Fr[64][34], Fi[64][34];
  __shared__ float Cr[2176], Ci[2176];
  __shared__ float twc[64], tws[64];
  const int tid = threadIdx.x;
  const int blk = blockIdx.x;
  const int b = blk >> 10;
  const int m = blk & 1023;
  float* img = xp + (size_t)blk * HW;

  if (tid < 64) {
    float ang = (2.f * 3.14159265358979323846f / 64.f) * (float)tid;
    twc[tid] = cosf(ang); tws[tid] = sinf(ang);
  }
  float r4[4], s4[4];
#pragma unroll
  for (int f = 0; f < 4; f++) {
    r4[f] = route[((size_t)b * 4 + f) * MEDC + m] * (1.f / 4096.f);
    s4[f] = sroute[((size_t)b * 4 + f) * MEDC + m];
  }
  __syncthreads();

#pragma unroll
  for (int half = 0; half < 2; half++) {
    {
      const int rh = tid & 31, n2 = tid >> 5;
      const int r = rh + half * 32;
      float xr[8], xi[8], Br[8], Bi[8];
#pragma unroll
      for (int n1 = 0; n1 < 8; n1++) { xr[n1] = img[r * 64 + 8 * n1 + n2]; xi[n1] = 0.f; }
      dft8<-1>(xr, xi, Br, Bi);
#pragma unroll
      for (int k1 = 0; k1 < 8; k1++) {
        int a = n2 * k1;
        float c = twc[a], s = tws[a];
        Cr[rh * 67 + k1 * 8 + n2] = Br[k1] * c + Bi[k1] * s;
        Ci[rh * 67 + k1 * 8 + n2] = Bi[k1] * c - Br[k1] * s;
      }
    }
    __syncthreads();
    {
      const int rh = tid & 31, k1 = tid >> 5;
      const int r = rh + half * 32;
      float xr[8], xi[8], Xr[8], Xi[8];
#pragma unroll
      for (int n2 = 0; n2 < 8; n2++) {
        xr[n2] = Cr[rh * 67 + k1 * 8 + n2];
        xi[n2] = Ci[rh * 67 + k1 * 8 + n2];
      }
      dft8<-1>(xr, xi, Xr, Xi);
      const int kmax = (k1 == 0) ? 5 : 4;
#pragma unroll
      for (int k2 = 0; k2 < 5; k2++) {
        if (k2 < kmax) {
          Fr[r][k1 + 8 * k2] = Xr[k2];
          Fi[r][k1 + 8 * k2] = Xi[k2];
        }
      }
    }
    __syncthreads();
  }

  for (int t = tid; t < 264; t += 256) {
    const int k = t % 33, n2 = t / 33;
    float xr[8], xi[8], Br[8], Bi[8];
#pragma unroll
    for (int n1 = 0; n1 < 8; n1++) { xr[n1] = Fr[8 * n1 + n2][k]; xi[n1] = Fi[8 * n1 + n2][k]; }
    dft8<-1>(xr, xi, Br, Bi);
#pragma unroll
    for (int k1 = 0; k1 < 8; k1++) {
      int a = n2 * k1;
      float c = twc[a], s = tws[a];
      Cr[(k1 * 8 + n2) * 34 + k] = Br[k1] * c + Bi[k1] * s;
      Ci[(k1 * 8 + n2) * 34 + k] = Bi[k1] * c - Br[k1] * s;
    }
  }
  __syncthreads();
  for (int t = tid; t < 264; t += 256) {
    const int k = t % 33, k1 = t / 33;
    float xr[8], xi[8], Xr[8], Xi[8];
#pragma unroll
    for (int n2 = 0; n2 < 8; n2++) {
      xr[n2] = Cr[(k1 * 8 + n2) * 34 + k];
      xi[n2] = Ci[(k1 * 8 + n2) * 34 + k];
    }
    dft8<-1>(xr, xi, Xr, Xi);
#pragma unroll
    for (int k2 = 0; k2 < 8; k2++) {
      const int kh = k1 + 8 * k2;
      const float* cwp = &cw[(size_t)(kh * 33 + k) * 8];
      float wre = r4[0] * cwp[0] + r4[1] * cwp[2] + r4[2] * cwp[4] + r4[3] * cwp[6];
      float wim = r4[0] * cwp[1] + r4[1] * cwp[3] + r4[2] * cwp[5] + r4[3] * cwp[7];
      Fr[kh][k] = Xr[k2] * wre - Xi[k2] * wim;
      Fi[kh][k] = Xr[k2] * wim + Xi[k2] * wre;
    }
  }
  __syncthreads();

  for (int t = tid; t < 264; t += 256) {
    const int k = t % 33, m2 = t / 33;
    float xr[8], xi[8], Br[8], Bi[8];
#pragma unroll
    for (int m1 = 0; m1 < 8; m1++) { xr[m1] = Fr[8 * m1 + m2][k]; xi[m1] = Fi[8 * m1 + m2][k]; }
    dft8<1>(xr, xi, Br, Bi);
#pragma unroll
    for (int h1 = 0; h1 < 8; h1++) {
      int a = m2 * h1;
      float c = twc[a], s = tws[a];
      Cr[(h1 * 8 + m2) * 34 + k] = Br[h1] * c - Bi[h1] * s;
      Ci[(h1 * 8 + m2) * 34 + k] = Bi[h1] * c + Br[h1] * s;
    }
  }
  __syncthreads();
  for (int t = tid; t < 264; t += 256) {
    const int k = t % 33, h1 = t / 33;
    float xr[8], xi[8], Xr[8], Xi[8];
#pragma unroll
    for (int m2 = 0; m2 < 8; m2++) {
      xr[m2] = Cr[(h1 * 8 + m2) * 34 + k];
      xi[m2] = Ci[(h1 * 8 + m2) * 34 + k];
    }
    dft8<1>(xr, xi, Xr, Xi);
#pragma unroll
    for (int h2 = 0; h2 < 8; h2++) {
      Fr[h1 + 8 * h2][k] = Xr[h2];
      Fi[h1 + 8 * h2][k] = Xi[h2];
    }
  }
  __syncthreads();

#pragma unroll
  for (int half = 0; half < 2; half++) {
    {
      const int rh = tid & 31, m2 = tid >> 5;
      const int r = rh + half * 32;
      float xr[8], xi[8], Br[8], Bi[8];
      if (m2 == 0) {
        xr[0] = Fr[r][0];  xi[0] = 0.f;
        xr[4] = Fr[r][32]; xi[4] = 0.f;
      } else {
        xr[0] = 2.f * Fr[r][m2]; xi[0] = 2.f * Fi[r][m2];
        xr[4] = 0.f; xi[4] = 0.f;
      }
#pragma unroll
      for (int m1 = 1; m1 < 4; m1++) {
        xr[m1] = 2.f * Fr[r][8 * m1 + m2];
        xi[m1] = 2.f * Fi[r][8 * m1 + m2];
      }
      xr[5] = 0.f; xi[5] = 0.f; xr[6] = 0.f; xi[6] = 0.f; xr[7] = 0.f; xi[7] = 0.f;
      dft8<1>(xr, xi, Br, Bi);
#pragma unroll
      for (int h1 = 0; h1 < 8; h1++) {
        int a = m2 * h1;
        float c = twc[a], s = tws[a];
        Cr[rh * 67 + h1 * 8 + m2] = Br[h1] * c - Bi[h1] * s;
        Ci[rh * 67 + h1 * 8 + m2] = Bi[h1] * c + Br[h1] * s;
      }
    }
    __syncthreads();
    {
      const int rh = tid & 31, h1 = tid >> 5;
      const int r = rh + half * 32;
      float xr[8], xi[8], Xr[8], Xi[8];
#pragma unroll
      for (int m2 = 0; m2 < 8; m2++) {
        xr[m2] = Cr[rh * 67 + h1 * 8 + m2];
        xi[m2] = Ci[rh * 67 + h1 * 8 + m2];
      }
      dft8<1>(xr, xi, Xr, Xi);
#pragma unroll
      for (int h2 = 0; h2 < 8; h2++) {
        const int w = h1 + 8 * h2;
        const int pix = r * 64 + w;
        float xv = img[pix];
        const float* sp = &spw[(size_t)pix * 4];
        float sw = s4[0] * sp[0] + s4[1] * sp[1] + s4[2] * sp[2] + s4[3] * sp[3];
        img[pix] = xv * sw + Xr[h2];
      }
    }
    __syncthreads();
  }
}

extern "C" void kernel_launch(void* const* d_in, const int* in_sizes, int n_in,
                              void* d_out, int out_size, void* d_ws, size_t ws_size,
                              hipStream_t stream) {
  const float* x          = (const float*)d_in[0];
  const float* w_pw1      = (const float*)d_in[1];
  const float* w_pw2      = (const float*)d_in[2];
  const float* star_scale = (const float*)d_in[3];
  const float* star_bias  = (const float*)d_in[4];
  const float* rw1w = (const float*)d_in[5];
  const float* rw1b = (const float*)d_in[6];
  const float* rwcw = (const float*)d_in[7];
  const float* rwcb = (const float*)d_in[8];
  const float* rw2w = (const float*)d_in[9];
  const float* rw2b = (const float*)d_in[10];
  const float* sp1w = (const float*)d_in[11];
  const float* sp1b = (const float*)d_in[12];
  const float* sp2w = (const float*)d_in[13];
  const float* sp2b = (const float*)d_in[14];
  const float* cw   = (const float*)d_in[15];
  const float* spw  = (const float*)d_in[16];

  if (ws_size < WS_END * sizeof(float)) return;

  float* ws = (float*)d_ws;
  float* xp = ws + XP_OFF;
  unsigned short* r1    = (unsigned short*)(ws + R1_OFF);
  unsigned short* xT    = (unsigned short*)(ws + XT_OFF);
  unsigned short* wconv = (unsigned short*)(ws + WCONV_OFF);
  unsigned short* wr1   = (unsigned short*)(ws + WR1_OFF);
  unsigned short* wrc   = (unsigned short*)(ws + WRC_OFF);
  unsigned short* wb1   = (unsigned short*)(ws + WB1_OFF);
  unsigned short* wb2   = (unsigned short*)(ws + WB2_OFF);
  float* meansum = ws + MEAN_OFF;
  float* agg     = ws + AGG_OFF;
  float* tap     = ws + TAP_OFF;
  float* route   = ws + ROUTE_OFF;
  float* sr      = ws + SR_OFF;
  float* out = (float*)d_out;

  hipMemsetAsync(meansum, 0, (4096 + 36864) * sizeof(float), stream);

  // bf16 prep
  xpose_bf16<<<dim3(128, 16, 16), 256, 0, stream>>>(x, xT);
  wconv_bf16<<<512, 256, 0, stream>>>(sp1w, wconv);
  cvt_bf16<<<2048, 256, 0, stream>>>(w_pw1, wb1, MEDC * DIMC);
  cvt_bf16<<<2048, 256, 0, stream>>>(w_pw2, wb2, DIMC * MEDC);
  cvt_bf16<<<512, 256, 0, stream>>>(rw1w, wr1, HRC * DIMC);
  cvt_bf16<<<256, 256, 0, stream>>>(rwcw, wrc, HRC * HRC);

  // routing branch (bf16 MFMA)
  gemm_bf16<1, 0><<<dim3(32, 2, 16), 256, 0, stream>>>(
      xT, wr1, rw1b, nullptr, r1, nullptr, nullptr, nullptr, DIMC, HRC);
  gemm_bf16<3, 0><<<dim3(32, 2, 16), 256, 0, stream>>>(
      r1, wrc, rwcb, nullptr, nullptr, meansum, nullptr, nullptr, HRC, HRC);
  route_softmax<<<dim3(4, 16), 256, 0, stream>>>(meansum, rw2w, rw2b, route);

  // spatial routing branch (bf16 MFMA conv)
  conv3_mfma<<<dim3(32, 2, 16), 256, 0, stream>>>(xT, wconv, sp1b, agg);
  tap_compute<<<16, 256, 0, stream>>>(agg, tap);
  sproute_softmax<<<dim3(4, 16), 256, 0, stream>>>(tap, sp2w, sp2b, sr);

  // main path (bf16 MFMA)
  gemm_bf16<2, 1><<<dim3(32, 8, 16), 256, 0, stream>>>(
      x, wb1, nullptr, xp, nullptr, nullptr, star_scale, star_bias, DIMC, MEDC);
  fft_filter<<<16384, 256, 0, stream>>>(xp, route, sr, cw, spw);
  gemm_bf16<0, 1><<<dim3(32, 4, 16), 256, 0, stream>>>(
      xp, wb2, nullptr, out, nullptr, nullptr, nullptr, nullptr, MEDC, DIMC);
}